// Round 5
// baseline (1008.743 us; speedup 1.0000x reference)
//
#include <hip/hip_runtime.h>
#include <math.h>

#define NBATCH 64
#define NCP    512
#define CPD    64
#define NF     256
#define WSZ    512
#define SD     128
#define NSAMP  65536
#define TPROP  8   // ||A||~0.13/step -> truncation error ~1e-14 abs, threshold ~1e-8
#define NSLICE 8
#define SLICE_ELEMS 2048
#define GRID_ALL 576   // 64 chain + 512 slice blocks; co-resident by __launch_bounds__(256,4)

__device__ __forceinline__ bool better(float v1, int i1, float v2, int i2) {
  // value descending, index ascending tie-break (matches jax argmax/top_k)
  return (v1 > v2) || (v1 == v2 && i1 < i2);
}

__device__ __forceinline__ void cswap(float& v1, int& i1, float& v2, int& i2) {
  if (better(v2, i2, v1, i1)) {
    float tv = v1; v1 = v2; v2 = tv;
    int   ti = i1; i1 = i2; i2 = ti;
  }
}

__device__ __forceinline__ void wave_argmax(float& v, int& i) {
#pragma unroll
  for (int off = 32; off > 0; off >>= 1) {
    float ov = __shfl_down(v, off);
    int   oi = __shfl_down(i, off);
    if (better(ov, oi, v, i)) { v = ov; i = oi; }
  }
}

// merge this lane's sorted-desc 8-list with partner lane's (xor off); both keep top-8
__device__ __forceinline__ void xor_merge8(float* m, int* mi, int off) {
  float lb[8]; int ib8[8];
#pragma unroll
  for (int k = 0; k < 8; k++) { lb[k] = __shfl_xor(m[k], off); ib8[k] = __shfl_xor(mi[k], off); }
  float x[8]; int xi[8];
#pragma unroll
  for (int k = 0; k < 8; k++) {   // top half of merged 16 (bitonic)
    const bool ta = better(m[k], mi[k], lb[7 - k], ib8[7 - k]);
    x[k]  = ta ? m[k]  : lb[7 - k];
    xi[k] = ta ? mi[k] : ib8[7 - k];
  }
  // bitonic clean desc: strides 4,2,1
  cswap(x[0], xi[0], x[4], xi[4]); cswap(x[1], xi[1], x[5], xi[5]);
  cswap(x[2], xi[2], x[6], xi[6]); cswap(x[3], xi[3], x[7], xi[7]);
  cswap(x[0], xi[0], x[2], xi[2]); cswap(x[1], xi[1], x[3], xi[3]);
  cswap(x[4], xi[4], x[6], xi[6]); cswap(x[5], xi[5], x[7], xi[7]);
  cswap(x[0], xi[0], x[1], xi[1]); cswap(x[2], xi[2], x[3], xi[3]);
  cswap(x[4], xi[4], x[5], xi[5]); cswap(x[6], xi[6], x[7], xi[7]);
#pragma unroll
  for (int k = 0; k < 8; k++) { m[k] = x[k]; mi[k] = xi[k]; }
}

// Manual grid barrier. SAFE ONLY because GRID_ALL=576 <= 4 blocks/CU * 256 CUs = 1024
// (guaranteed by __launch_bounds__(256,4) -> VGPR<=128, LDS ~7KB): every block is
// resident before any spins, so no dispatch-order deadlock is possible.
// bar must be zeroed (hipMemsetAsync) before each launch.
__device__ __forceinline__ void grid_barrier(int* bar, int tid) {
  __syncthreads();                       // all waves drain their own vmcnt (writes done)
  if (tid == 0) {
    __threadfence();                     // device-scope release: publish prior writes
    __hip_atomic_fetch_add(bar, 1, __ATOMIC_RELEASE, __HIP_MEMORY_SCOPE_AGENT);
    while (__hip_atomic_load(bar, __ATOMIC_ACQUIRE, __HIP_MEMORY_SCOPE_AGENT) < GRID_ALL)
      __builtin_amdgcn_s_sleep(2);
    __threadfence();                     // device-scope acquire: invalidate stale cache
  }
  __syncthreads();
}

// ---------------- fused kernel ----------------
// Phase 1: blocks 0..63 = S-chain + R;  blocks 64..575 = (batch,slice) selection
//          (+ P2 quarter on first 256 slice blocks, dirac shift on s==0)
// Phase 2: blocks 0..63 = per-batch top-8 combine (ONCE, was 2048x redundant in k_out)
// Phase 3: all blocks = output assembly, 2048 chunks strided over 576 blocks
__global__ __launch_bounds__(256, 4) void k_all(
    const float* __restrict__ cpc, const float* __restrict__ times,
    const float* __restrict__ lookup,
    const float* __restrict__ proj, const float* __restrict__ Amat,
    const float* __restrict__ Bmat, const float* __restrict__ Cmat,
    const float* __restrict__ Dmat,
    float* __restrict__ P2, float* __restrict__ R,
    float* __restrict__ pmax, float* __restrict__ psum,
    float* __restrict__ pcv, int* __restrict__ pci,
    int* __restrict__ pshift,
    float* __restrict__ vals, int* __restrict__ cidx, int* __restrict__ fidx,
    float* __restrict__ out, int* __restrict__ bar) {
  const int t = threadIdx.x;
  const int bid = blockIdx.x;

  // chain-path LDS (NOTE: A stays in L2 — r4 proved LDS-staging A costs ~2us, r2 proved
  // per-thread register copies trigger remat pathology. L2 streaming is the proven form.)
  __shared__ __align__(16) float sjall[SD * 8];   // 4 KB, [i][j] layout for float4 broadcast
  __shared__ float sb[2][SD];
  __shared__ float sred[256];
  // slice-path LDS (small)
  __shared__ float wred[4];
  __shared__ int   wredi[4];
  __shared__ int   sRow;
  __shared__ float wlv[32];
  __shared__ int   wli[32];
  __shared__ float sSmax;

  // ================= Phase 1 =================
  if (bid < CPD) {
    // ----- S-chain: s_j = proj_c @ B @ A^j, then R[j,c,:] = s_j @ C -----
    const int c = bid;
    const int d = t & 127, h = t >> 7;
    {
      // s0 partials: K-split 2, unroll 16 -> 16 loads in flight per batch
      const float* Bp = Bmat + (size_t)(h * 256) * SD + d;
      const float* pv = proj + (size_t)c * WSZ + h * 256;  // wave-uniform addresses
      float acc[16];
#pragma unroll
      for (int k = 0; k < 16; k++) acc[k] = 0.f;
#pragma unroll 2
      for (int kb = 0; kb < 256; kb += 16) {
#pragma unroll
        for (int u = 0; u < 16; u++)
          acc[u] = fmaf(pv[kb + u], Bp[(size_t)(kb + u) * SD], acc[u]);
      }
      float s8 = 0.f;
#pragma unroll
      for (int k = 0; k < 16; k++) s8 += acc[k];
      sred[t] = s8;
    }
    __syncthreads();
    if (t < SD) sb[0][t] = sred[t] + sred[t + 128];
    __syncthreads();

    int cur = 0;
    for (int j = 0; j < TPROP; j++) {
      if (t < SD) sjall[t * 8 + j] = sb[cur][t];
      // next state: K-split 2 over L2-resident A
      float a0 = 0.f, a1 = 0.f, a2 = 0.f, a3 = 0.f;
      const float* Ah = Amat + (size_t)(h * 64) * SD + d;
      const float* sh = sb[cur] + h * 64;
#pragma unroll
      for (int i = 0; i < 64; i += 4) {
        const float4 sv = *(const float4*)(sh + i);
        a0 = fmaf(sv.x, Ah[(size_t)(i + 0) * SD], a0);
        a1 = fmaf(sv.y, Ah[(size_t)(i + 1) * SD], a1);
        a2 = fmaf(sv.z, Ah[(size_t)(i + 2) * SD], a2);
        a3 = fmaf(sv.w, Ah[(size_t)(i + 3) * SD], a3);
      }
      sred[t] = (a0 + a1) + (a2 + a3);
      __syncthreads();
      if (t < SD) sb[cur ^ 1][t] = sred[t] + sred[t + 128];
      __syncthreads();
      cur ^= 1;
    }

    // ----- R pass: one sweep over C, 16 accumulators (8 j x 2 column halves) -----
    float r0[8], r1[8];
#pragma unroll
    for (int k = 0; k < 8; k++) { r0[k] = 0.f; r1[k] = 0.f; }
    const float* Cp = Cmat + t;
#pragma unroll 4
    for (int i = 0; i < SD; i++) {
      const float4 sA = *(const float4*)(sjall + i * 8);      // s_{0..3}[i] broadcast
      const float4 sB = *(const float4*)(sjall + i * 8 + 4);  // s_{4..7}[i]
      const float c0 = Cp[(size_t)i * WSZ];
      const float c1 = Cp[(size_t)i * WSZ + 256];
      r0[0] = fmaf(sA.x, c0, r0[0]); r1[0] = fmaf(sA.x, c1, r1[0]);
      r0[1] = fmaf(sA.y, c0, r0[1]); r1[1] = fmaf(sA.y, c1, r1[1]);
      r0[2] = fmaf(sA.z, c0, r0[2]); r1[2] = fmaf(sA.z, c1, r1[2]);
      r0[3] = fmaf(sA.w, c0, r0[3]); r1[3] = fmaf(sA.w, c1, r1[3]);
      r0[4] = fmaf(sB.x, c0, r0[4]); r1[4] = fmaf(sB.x, c1, r1[4]);
      r0[5] = fmaf(sB.y, c0, r0[5]); r1[5] = fmaf(sB.y, c1, r1[5]);
      r0[6] = fmaf(sB.z, c0, r0[6]); r1[6] = fmaf(sB.z, c1, r1[6]);
      r0[7] = fmaf(sB.w, c0, r0[7]); r1[7] = fmaf(sB.w, c1, r1[7]);
    }
#pragma unroll
    for (int j = 0; j < 8; j++) {
      R[((size_t)j * CPD + c) * WSZ + t]       = r0[j];
      R[((size_t)j * CPD + c) * WSZ + t + 256] = r1[j];
    }
  } else {
    const int sbid = bid - CPD;
    const int b = sbid >> 3, s = sbid & 7;
    const int lane = t & 63, wv = t >> 6;

    // --- cpc argmax (redundant across the 8 slice blocks; 2 KB, cheap) ---
    {
      float v0 = cpc[b * NCP + t];
      float v1 = cpc[b * NCP + t + 256];
      float bv = v0; int bi = t;
      if (better(v1, t + 256, bv, bi)) { bv = v1; bi = t + 256; }
      wave_argmax(bv, bi);
      if (lane == 0) { wred[wv] = bv; wredi[wv] = bi; }
      __syncthreads();
      if (t == 0) {
        float fv = wred[0]; int fi = wredi[0];
#pragma unroll
        for (int q = 1; q < 4; q++)
          if (better(wred[q], wredi[q], fv, fi)) { fv = wred[q]; fi = wredi[q]; }
        sRow = fi;
      }
      __syncthreads();
    }
    const float* row = lookup + (size_t)sRow * (CPD * NF);
    const float4* row4 = (const float4*)(row + s * SLICE_ELEMS);

    // --- load 8 elements (2 independent float4) ---
    const float4 va = row4[t];
    const float4 vb = row4[t + 256];
    const int gbase = s * SLICE_ELEMS;
    float ev[8] = {va.x, va.y, va.z, va.w, vb.x, vb.y, vb.z, vb.w};
    int   ei[8] = {gbase + t * 4,        gbase + t * 4 + 1,
                   gbase + t * 4 + 2,    gbase + t * 4 + 3,
                   gbase + 1024 + t * 4, gbase + 1024 + t * 4 + 1,
                   gbase + 1024 + t * 4 + 2, gbase + 1024 + t * 4 + 3};

    // --- per-thread sort desc (static bubble network, registers) ---
    float m[8]; int mi[8];
#pragma unroll
    for (int k = 0; k < 8; k++) { m[k] = ev[k]; mi[k] = ei[k]; }
#pragma unroll
    for (int i = 0; i < 7; i++)
#pragma unroll
      for (int j = 0; j < 7 - i; j++) cswap(m[j], mi[j], m[j + 1], mi[j + 1]);

    // --- wave-level merge: 6 shuffle rounds, no barriers, no LDS ---
    xor_merge8(m, mi, 1);  xor_merge8(m, mi, 2);  xor_merge8(m, mi, 4);
    xor_merge8(m, mi, 8);  xor_merge8(m, mi, 16); xor_merge8(m, mi, 32);

    if (lane < 8) { wlv[wv * 8 + lane] = m[lane]; wli[wv * 8 + lane] = mi[lane]; }
    __syncthreads();

    // --- wave 0: bitonic sort-32 of the 4 wave lists via shuffles ---
    if (wv == 0) {
      float v = (lane < 32) ? wlv[lane] : -3.4e38f;
      int   i = (lane < 32) ? wli[lane] : 0x7fffffff;
#pragma unroll
      for (int k = 2; k <= 32; k <<= 1) {
#pragma unroll
        for (int j = k >> 1; j > 0; j >>= 1) {
          const float pv = __shfl_xor(v, j);
          const int   pi = __shfl_xor(i, j);
          const bool keepBetter = (((lane & k) == 0) == ((lane & j) == 0));
          if (keepBetter == better(pv, pi, v, i)) { v = pv; i = pi; }
        }
      }
      if (lane == 0) sSmax = v;
      if (lane < 8) { pcv[b * 64 + s * 8 + lane] = v; pci[b * 64 + s * 8 + lane] = i; }
    }
    __syncthreads();
    const float smax = sSmax;

    // --- partial exp-sum (8 independent exps per thread) ---
    float se = 0.f;
#pragma unroll
    for (int k = 0; k < 8; k++) se += __expf(ev[k] - smax);
#pragma unroll
    for (int off = 32; off > 0; off >>= 1) se += __shfl_down(se, off);
    if (lane == 0) wred[wv] = se;
    __syncthreads();
    if (t == 0) {
      pmax[b * 8 + s] = smax;
      psum[b * 8 + s] = (wred[0] + wred[1]) + (wred[2] + wred[3]);
    }
    __syncthreads();  // protect wred against reuse below

    // --- dirac shift (slice 0 only): argmax over times[b,0,:256] ---
    if (s == 0) {
      float tv = times[b * NF + t]; int ti = t;
      wave_argmax(tv, ti);
      if (lane == 0) { wred[wv] = tv; wredi[wv] = ti; }
      __syncthreads();
      if (t == 0) {
        float fv = wred[0]; int fi = wredi[0];
#pragma unroll
        for (int q = 1; q < 4; q++)
          if (better(wred[q], wredi[q], fv, fi)) { fv = wred[q]; fi = wredi[q]; }
        pshift[b] = fi * (NSAMP / NF);
      }
    }

    // --- P2 quarter-row (first 256 slice blocks): P2[c,q*128:+128] = proj[c,:] @ D[:,cols] ---
    if (sbid < 256) {
      const int c2 = sbid >> 2, q = sbid & 3;
      const int col = q * 128 + (t & 127);
      const int uh = t >> 7;                      // K-split 2 over u
      const float* pr = proj + (size_t)c2 * WSZ + uh * 256;  // uniform -> scalar loads
      const float* Dp = Dmat + (size_t)(uh * 256) * WSZ + col;
      float a[8];
#pragma unroll
      for (int k = 0; k < 8; k++) a[k] = 0.f;
#pragma unroll 2
      for (int u = 0; u < 256; u += 8) {
#pragma unroll
        for (int v = 0; v < 8; v++)
          a[v] = fmaf(pr[u + v], Dp[(size_t)(u + v) * WSZ], a[v]);
      }
      float acc = 0.f;
#pragma unroll
      for (int k = 0; k < 8; k++) acc += a[k];
      sred[t] = acc;
      __syncthreads();
      if (t < 128) P2[(size_t)c2 * WSZ + q * 128 + t] = sred[t] + sred[t + 128];
    }
  }

  grid_barrier(bar + 0, t);

  // ================= Phase 2: per-batch combine, ONCE (blocks 0..63) =================
  if (bid < NBATCH) {
    const int b = bid;
    if (t < 64) {
      const int sl = t >> 3;
      float M = pmax[b * 8 + sl];
#pragma unroll
      for (int off = 1; off < 64; off <<= 1) M = fmaxf(M, __shfl_xor(M, off));
      float ps = ((t & 7) == 0) ? psum[b * 8 + sl] * __expf(pmax[b * 8 + sl] - M) : 0.f;
#pragma unroll
      for (int off = 1; off < 64; off <<= 1) ps += __shfl_xor(ps, off);
      float cvv = pcv[b * 64 + t]; int cii = pci[b * 64 + t];
      for (int p = 0; p < 8; p++) {
        float v = cvv; int i = cii;
#pragma unroll
        for (int off = 1; off < 64; off <<= 1) {
          float ov = __shfl_xor(v, off); int oi = __shfl_xor(i, off);
          if (better(ov, oi, v, i)) { v = ov; i = oi; }
        }
        if (t == 0) {
          vals[b * 8 + p] = __expf(v - M) / ps;
          cidx[b * 8 + p] = i / NF;
          fidx[b * 8 + p] = i % NF;
        }
        if (cii == i) cvv = -3.4e38f;
      }
    }
  }

  grid_barrier(bar + 1, t);

  // ================= Phase 3: output assembly (2048 chunks over 576 blocks) =================
  for (int chunk = bid; chunk < NBATCH * 32; chunk += GRID_ALL) {
    const int b = chunk >> 5;
    const int c5 = chunk & 31;
    const int shift = pshift[b];
    float lvv[8]; int lcc[8], lff[8];
#pragma unroll
    for (int k = 0; k < 8; k++) {
      lvv[k] = vals[b * 8 + k];
      lcc[k] = cidx[b * 8 + k];
      lff[k] = fidx[b * 8 + k];
    }
#pragma unroll 2
    for (int half = 0; half < 2; half++) {
      const int n = c5 * 2048 + half * 1024 + t * 4;  // 4 samples per thread per half
      const int m = n - shift;              // shift multiple of 256 -> 4 samples share frames
      float o[4] = {0.f, 0.f, 0.f, 0.f};
      if (m >= 0) {
        const int f1 = m >> 8;
        const int w1 = m & 255;
        float a[4] = {0.f, 0.f, 0.f, 0.f};
        float g[4] = {0.f, 0.f, 0.f, 0.f};
        const bool hasf2 = (f1 > 0);
#pragma unroll
        for (int k = 0; k < 8; k++) {
          const float v = lvv[k];
          const int c = lcc[k];
          const int d1 = f1 - lff[k];
          if (d1 >= 0 && d1 < TPROP) {
            const float4 q = *(const float4*)(R + ((size_t)(d1 * CPD + c)) * WSZ + w1);
            a[0] += v * q.x; a[1] += v * q.y; a[2] += v * q.z; a[3] += v * q.w;
          }
          if (d1 == 0) {
            const float4 q = *(const float4*)(P2 + (size_t)c * WSZ + w1);
            a[0] += v * q.x; a[1] += v * q.y; a[2] += v * q.z; a[3] += v * q.w;
          }
          if (hasf2) {
            const int d2 = d1 - 1;
            if (d2 >= 0 && d2 < TPROP) {
              const float4 q = *(const float4*)(R + ((size_t)(d2 * CPD + c)) * WSZ + w1 + 256);
              g[0] += v * q.x; g[1] += v * q.y; g[2] += v * q.z; g[3] += v * q.w;
            }
            if (d2 == 0) {
              const float4 q = *(const float4*)(P2 + (size_t)c * WSZ + w1 + 256);
              g[0] += v * q.x; g[1] += v * q.y; g[2] += v * q.z; g[3] += v * q.w;
            }
          }
        }
        const float k2pi = 6.283185307179586f / (float)WSZ;
#pragma unroll
        for (int i = 0; i < 4; i++) {
          const float cs = __cosf(k2pi * (float)(w1 + i));
          const float wa = 0.5f * (1.f - cs);
          const float wb = 0.5f * (1.f + cs);
          o[i] = wa * a[i] + wb * g[i];
        }
      }
      float4 ov = make_float4(o[0], o[1], o[2], o[3]);
      *(float4*)(out + (size_t)b * NSAMP + n) = ov;
    }
  }
}

extern "C" void kernel_launch(void* const* d_in, const int* in_sizes, int n_in,
                              void* d_out, int out_size, void* d_ws, size_t ws_size,
                              hipStream_t stream) {
  const float* cpc    = (const float*)d_in[0];
  const float* times  = (const float*)d_in[1];
  const float* lookup = (const float*)d_in[2];
  const float* proj   = (const float*)d_in[3];
  const float* Amat   = (const float*)d_in[4];
  const float* Bmat   = (const float*)d_in[5];
  const float* Cmat   = (const float*)d_in[6];
  const float* Dmat   = (const float*)d_in[7];
  float* out = (float*)d_out;

  // ws floats: vals[512] cidx[512] fidx[512] pshift[64] P2[32768] R[262144] [S unused 65536]
  //            pmax[512] psum[512] pcv[4096] pci[4096] bar[2]
  float* w      = (float*)d_ws;
  float* vals   = w;
  int*   cidx   = (int*)(w + 512);
  int*   fidx   = (int*)(w + 1024);
  int*   pshift = (int*)(w + 1536);
  float* P2     = w + 1600;
  float* R      = P2 + CPD * WSZ;
  float* S_unused = R + (size_t)TPROP * CPD * WSZ;
  float* pmax   = S_unused + (size_t)TPROP * CPD * SD;
  float* psum   = pmax + NBATCH * NSLICE;
  float* pcv    = psum + NBATCH * NSLICE;
  int*   pci    = (int*)(pcv + NBATCH * NSLICE * 8);
  int*   bar    = (int*)(pci + NBATCH * NSLICE * 8);

  hipMemsetAsync(bar, 0, 2 * sizeof(int), stream);
  hipLaunchKernelGGL(k_all, dim3(GRID_ALL), dim3(256), 0, stream,
                     cpc, times, lookup, proj, Amat, Bmat, Cmat, Dmat,
                     P2, R, pmax, psum, pcv, pci, pshift,
                     vals, cidx, fidx, out, bar);
}

// Round 6
// 125.137 us; speedup vs baseline: 8.0611x; 8.0611x over previous
//
#include <hip/hip_runtime.h>
#include <math.h>

#define NBATCH 64
#define NCP    512
#define CPD    64
#define NF     256
#define WSZ    512
#define SD     128
#define NSAMP  65536
#define TPROP  8   // ||A||~0.13/step -> truncation error ~1e-14 abs, threshold ~1e-8
#define NSLICE 8
#define SLICE_ELEMS 2048

// ---------------------------------------------------------------------------
// SESSION LEDGER (do not retry these):
//  r2: A in per-thread VGPR array -> compiler pinned VGPR=60, rematerialized loads
//      in the serial loop; k_scan 55-66us (vs <44 here). REGRESSION.
//  r4: A staged in 64KB LDS -> +2.4us vs L2 streaming. The 64 chain blocks get
//      ~1 load-latency/step from L2 anyway (64 independent loads in flight);
//      LDS staging only adds the fill cost. REGRESSION.
//  r5: single-kernel fusion with manual agent-scope spin barrier -> ~950us idle:
//      cross-XCD L2 non-coherence makes the spin observe stale values until
//      eviction. VALUBusy 0.75%. CATASTROPHIC. Do not spin across XCDs.
//  Best = this form (r3): 126.06us. ~88us of the window is harness poison-fill
//      (2 x 44us fillBufferAligned on the 256MB workspace); controllable part ~38us.
// ---------------------------------------------------------------------------

__device__ __forceinline__ bool better(float v1, int i1, float v2, int i2) {
  // value descending, index ascending tie-break (matches jax argmax/top_k)
  return (v1 > v2) || (v1 == v2 && i1 < i2);
}

__device__ __forceinline__ void cswap(float& v1, int& i1, float& v2, int& i2) {
  if (better(v2, i2, v1, i1)) {
    float tv = v1; v1 = v2; v2 = tv;
    int   ti = i1; i1 = i2; i2 = ti;
  }
}

__device__ __forceinline__ void wave_argmax(float& v, int& i) {
#pragma unroll
  for (int off = 32; off > 0; off >>= 1) {
    float ov = __shfl_down(v, off);
    int   oi = __shfl_down(i, off);
    if (better(ov, oi, v, i)) { v = ov; i = oi; }
  }
}

// merge this lane's sorted-desc 8-list with partner lane's (xor off); both keep top-8
__device__ __forceinline__ void xor_merge8(float* m, int* mi, int off) {
  float lb[8]; int ib8[8];
#pragma unroll
  for (int k = 0; k < 8; k++) { lb[k] = __shfl_xor(m[k], off); ib8[k] = __shfl_xor(mi[k], off); }
  float x[8]; int xi[8];
#pragma unroll
  for (int k = 0; k < 8; k++) {   // top half of merged 16 (bitonic)
    const bool ta = better(m[k], mi[k], lb[7 - k], ib8[7 - k]);
    x[k]  = ta ? m[k]  : lb[7 - k];
    xi[k] = ta ? mi[k] : ib8[7 - k];
  }
  // bitonic clean desc: strides 4,2,1
  cswap(x[0], xi[0], x[4], xi[4]); cswap(x[1], xi[1], x[5], xi[5]);
  cswap(x[2], xi[2], x[6], xi[6]); cswap(x[3], xi[3], x[7], xi[7]);
  cswap(x[0], xi[0], x[2], xi[2]); cswap(x[1], xi[1], x[3], xi[3]);
  cswap(x[4], xi[4], x[6], xi[6]); cswap(x[5], xi[5], x[7], xi[7]);
  cswap(x[0], xi[0], x[1], xi[1]); cswap(x[2], xi[2], x[3], xi[3]);
  cswap(x[4], xi[4], x[5], xi[5]); cswap(x[6], xi[6], x[7], xi[7]);
#pragma unroll
  for (int k = 0; k < 8; k++) { m[k] = x[k]; mi[k] = xi[k]; }
}

// ---------------- K1: blocks 0..63 = S-chain + R (longest pole, dispatched first);
//                     blocks 64..575 = (batch, slice) selection; first 256 also do a P2 quarter ----------------
__global__ __launch_bounds__(256) void k_scan(
    const float* __restrict__ cpc, const float* __restrict__ times,
    const float* __restrict__ lookup,
    const float* __restrict__ proj, const float* __restrict__ Amat,
    const float* __restrict__ Bmat, const float* __restrict__ Cmat,
    const float* __restrict__ Dmat,
    float* __restrict__ P2, float* __restrict__ R,
    float* __restrict__ pmax, float* __restrict__ psum,
    float* __restrict__ pcv, int* __restrict__ pci,
    int* __restrict__ pshift) {
  const int t = threadIdx.x;
  const int bid = blockIdx.x;

  // chain-path LDS. A stays in L2 (see ledger: r2/r4 alternatives regressed).
  __shared__ __align__(16) float sjall[SD * 8];   // 4 KB, [i][j] layout for float4 broadcast
  __shared__ float sb[2][SD];
  __shared__ float sred[256];
  // slice-path LDS (small)
  __shared__ float wred[4];
  __shared__ int   wredi[4];
  __shared__ int   sRow;
  __shared__ float wlv[32];
  __shared__ int   wli[32];
  __shared__ float sSmax;

  if (bid < CPD) {
    // ----- S-chain: s_j = proj_c @ B @ A^j, then R[j,c,:] = s_j @ C (no global S round-trip) -----
    const int c = bid;
    const int d = t & 127, h = t >> 7;
    {
      // s0 partials: K-split 2, unroll 16 -> 16 loads in flight per batch
      const float* Bp = Bmat + (size_t)(h * 256) * SD + d;
      const float* pv = proj + (size_t)c * WSZ + h * 256;  // wave-uniform addresses
      float acc[16];
#pragma unroll
      for (int k = 0; k < 16; k++) acc[k] = 0.f;
#pragma unroll 2
      for (int kb = 0; kb < 256; kb += 16) {
#pragma unroll
        for (int u = 0; u < 16; u++)
          acc[u] = fmaf(pv[kb + u], Bp[(size_t)(kb + u) * SD], acc[u]);
      }
      float s8 = 0.f;
#pragma unroll
      for (int k = 0; k < 16; k++) s8 += acc[k];
      sred[t] = s8;
    }
    __syncthreads();
    if (t < SD) sb[0][t] = sred[t] + sred[t + 128];
    __syncthreads();

    int cur = 0;
    for (int j = 0; j < TPROP; j++) {
      if (t < SD) sjall[t * 8 + j] = sb[cur][t];
      // next state: K-split 2 over L2-resident A
      float a0 = 0.f, a1 = 0.f, a2 = 0.f, a3 = 0.f;
      const float* Ah = Amat + (size_t)(h * 64) * SD + d;
      const float* sh = sb[cur] + h * 64;
#pragma unroll
      for (int i = 0; i < 64; i += 4) {
        const float4 sv = *(const float4*)(sh + i);
        a0 = fmaf(sv.x, Ah[(size_t)(i + 0) * SD], a0);
        a1 = fmaf(sv.y, Ah[(size_t)(i + 1) * SD], a1);
        a2 = fmaf(sv.z, Ah[(size_t)(i + 2) * SD], a2);
        a3 = fmaf(sv.w, Ah[(size_t)(i + 3) * SD], a3);
      }
      sred[t] = (a0 + a1) + (a2 + a3);
      __syncthreads();
      if (t < SD) sb[cur ^ 1][t] = sred[t] + sred[t + 128];
      __syncthreads();
      cur ^= 1;
    }

    // ----- R pass: one sweep over C, 16 accumulators (8 j x 2 column halves) -----
    float r0[8], r1[8];
#pragma unroll
    for (int k = 0; k < 8; k++) { r0[k] = 0.f; r1[k] = 0.f; }
    const float* Cp = Cmat + t;
#pragma unroll 4
    for (int i = 0; i < SD; i++) {
      const float4 sA = *(const float4*)(sjall + i * 8);      // s_{0..3}[i] broadcast
      const float4 sB = *(const float4*)(sjall + i * 8 + 4);  // s_{4..7}[i]
      const float c0 = Cp[(size_t)i * WSZ];
      const float c1 = Cp[(size_t)i * WSZ + 256];
      r0[0] = fmaf(sA.x, c0, r0[0]); r1[0] = fmaf(sA.x, c1, r1[0]);
      r0[1] = fmaf(sA.y, c0, r0[1]); r1[1] = fmaf(sA.y, c1, r1[1]);
      r0[2] = fmaf(sA.z, c0, r0[2]); r1[2] = fmaf(sA.z, c1, r1[2]);
      r0[3] = fmaf(sA.w, c0, r0[3]); r1[3] = fmaf(sA.w, c1, r1[3]);
      r0[4] = fmaf(sB.x, c0, r0[4]); r1[4] = fmaf(sB.x, c1, r1[4]);
      r0[5] = fmaf(sB.y, c0, r0[5]); r1[5] = fmaf(sB.y, c1, r1[5]);
      r0[6] = fmaf(sB.z, c0, r0[6]); r1[6] = fmaf(sB.z, c1, r1[6]);
      r0[7] = fmaf(sB.w, c0, r0[7]); r1[7] = fmaf(sB.w, c1, r1[7]);
    }
#pragma unroll
    for (int j = 0; j < 8; j++) {
      R[((size_t)j * CPD + c) * WSZ + t]       = r0[j];
      R[((size_t)j * CPD + c) * WSZ + t + 256] = r1[j];
    }
    return;
  }

  const int sbid = bid - CPD;
  const int b = sbid >> 3, s = sbid & 7;
  const int lane = t & 63, wv = t >> 6;

  // --- cpc argmax (redundant across the 8 slice blocks; 2 KB, cheap) ---
  {
    float v0 = cpc[b * NCP + t];
    float v1 = cpc[b * NCP + t + 256];
    float bv = v0; int bi = t;
    if (better(v1, t + 256, bv, bi)) { bv = v1; bi = t + 256; }
    wave_argmax(bv, bi);
    if (lane == 0) { wred[wv] = bv; wredi[wv] = bi; }
    __syncthreads();
    if (t == 0) {
      float fv = wred[0]; int fi = wredi[0];
#pragma unroll
      for (int q = 1; q < 4; q++)
        if (better(wred[q], wredi[q], fv, fi)) { fv = wred[q]; fi = wredi[q]; }
      sRow = fi;
    }
    __syncthreads();
  }
  const float* row = lookup + (size_t)sRow * (CPD * NF);
  const float4* row4 = (const float4*)(row + s * SLICE_ELEMS);

  // --- load 8 elements (2 independent float4) ---
  const float4 va = row4[t];
  const float4 vb = row4[t + 256];
  const int gbase = s * SLICE_ELEMS;
  float ev[8] = {va.x, va.y, va.z, va.w, vb.x, vb.y, vb.z, vb.w};
  int   ei[8] = {gbase + t * 4,        gbase + t * 4 + 1,
                 gbase + t * 4 + 2,    gbase + t * 4 + 3,
                 gbase + 1024 + t * 4, gbase + 1024 + t * 4 + 1,
                 gbase + 1024 + t * 4 + 2, gbase + 1024 + t * 4 + 3};

  // --- per-thread sort desc (static bubble network, registers) ---
  float m[8]; int mi[8];
#pragma unroll
  for (int k = 0; k < 8; k++) { m[k] = ev[k]; mi[k] = ei[k]; }
#pragma unroll
  for (int i = 0; i < 7; i++)
#pragma unroll
    for (int j = 0; j < 7 - i; j++) cswap(m[j], mi[j], m[j + 1], mi[j + 1]);

  // --- wave-level merge: 6 shuffle rounds, no barriers, no LDS ---
  xor_merge8(m, mi, 1);  xor_merge8(m, mi, 2);  xor_merge8(m, mi, 4);
  xor_merge8(m, mi, 8);  xor_merge8(m, mi, 16); xor_merge8(m, mi, 32);

  if (lane < 8) { wlv[wv * 8 + lane] = m[lane]; wli[wv * 8 + lane] = mi[lane]; }
  __syncthreads();

  // --- wave 0: bitonic sort-32 of the 4 wave lists via shuffles ---
  if (wv == 0) {
    float v = (lane < 32) ? wlv[lane] : -3.4e38f;
    int   i = (lane < 32) ? wli[lane] : 0x7fffffff;
#pragma unroll
    for (int k = 2; k <= 32; k <<= 1) {
#pragma unroll
      for (int j = k >> 1; j > 0; j >>= 1) {
        const float pv = __shfl_xor(v, j);
        const int   pi = __shfl_xor(i, j);
        const bool keepBetter = (((lane & k) == 0) == ((lane & j) == 0));
        if (keepBetter == better(pv, pi, v, i)) { v = pv; i = pi; }
      }
    }
    if (lane == 0) sSmax = v;
    if (lane < 8) { pcv[b * 64 + s * 8 + lane] = v; pci[b * 64 + s * 8 + lane] = i; }
  }
  __syncthreads();
  const float smax = sSmax;

  // --- partial exp-sum (8 independent exps per thread) ---
  float se = 0.f;
#pragma unroll
  for (int k = 0; k < 8; k++) se += __expf(ev[k] - smax);
#pragma unroll
  for (int off = 32; off > 0; off >>= 1) se += __shfl_down(se, off);
  if (lane == 0) wred[wv] = se;
  __syncthreads();
  if (t == 0) {
    pmax[b * 8 + s] = smax;
    psum[b * 8 + s] = (wred[0] + wred[1]) + (wred[2] + wred[3]);
  }
  __syncthreads();  // protect wred against reuse below

  // --- dirac shift (slice 0 only): argmax over times[b,0,:256] ---
  if (s == 0) {
    float tv = times[b * NF + t]; int ti = t;
    wave_argmax(tv, ti);
    if (lane == 0) { wred[wv] = tv; wredi[wv] = ti; }
    __syncthreads();
    if (t == 0) {
      float fv = wred[0]; int fi = wredi[0];
#pragma unroll
      for (int q = 1; q < 4; q++)
        if (better(wred[q], wredi[q], fv, fi)) { fv = wred[q]; fi = wredi[q]; }
      pshift[b] = fi * (NSAMP / NF);
    }
  }

  // --- P2 quarter-row (first 256 slice blocks): P2[c, q*128 : q*128+128] = proj[c,:] @ D[:, cols] ---
  if (sbid < 256) {
    const int c2 = sbid >> 2, q = sbid & 3;
    const int col = q * 128 + (t & 127);
    const int uh = t >> 7;                      // K-split 2 over u
    const float* pr = proj + (size_t)c2 * WSZ + uh * 256;  // uniform -> scalar loads
    const float* Dp = Dmat + (size_t)(uh * 256) * WSZ + col;
    float a[8];
#pragma unroll
    for (int k = 0; k < 8; k++) a[k] = 0.f;
#pragma unroll 2
    for (int u = 0; u < 256; u += 8) {
#pragma unroll
      for (int v = 0; v < 8; v++)
        a[v] = fmaf(pr[u + v], Dp[(size_t)(u + v) * WSZ], a[v]);
    }
    float acc = 0.f;
#pragma unroll
    for (int k = 0; k < 8; k++) acc += a[k];
    sred[t] = acc;
    __syncthreads();
    if (t < 128) P2[(size_t)c2 * WSZ + q * 128 + t] = sred[t] + sred[t + 128];
  }
}

// ---------------- K2: per-block redundant top-8 combine (1 wave, deterministic) + output assembly ----------------
// 2048 blocks: 32 per batch, each covering 2048 samples (two float4 per thread)
__global__ __launch_bounds__(256) void k_out(
    const float* __restrict__ pmax, const float* __restrict__ psum,
    const float* __restrict__ pcv, const int* __restrict__ pci,
    const int* __restrict__ pshift,
    const float* __restrict__ P2, const float* __restrict__ R,
    float* __restrict__ out) {
  const int b = blockIdx.x >> 5;        // 32 blocks per batch
  const int chunk = blockIdx.x & 31;
  const int t = threadIdx.x;
  __shared__ float lv[8];
  __shared__ int   lc[8];
  __shared__ int   lf[8];

  const int shift = pshift[b];          // issue early: latency hides under the combine

  if (t < 64) {
    // merge 8 slice top-8 lists for batch b (identical in every block of this batch)
    const int sl = t >> 3;
    float M = pmax[b * 8 + sl];
#pragma unroll
    for (int off = 1; off < 64; off <<= 1) M = fmaxf(M, __shfl_xor(M, off));
    float ps = ((t & 7) == 0) ? psum[b * 8 + sl] * __expf(pmax[b * 8 + sl] - M) : 0.f;
#pragma unroll
    for (int off = 1; off < 64; off <<= 1) ps += __shfl_xor(ps, off);
    float cvv = pcv[b * 64 + t]; int cii = pci[b * 64 + t];
    for (int p = 0; p < 8; p++) {
      float v = cvv; int i = cii;
#pragma unroll
      for (int off = 1; off < 64; off <<= 1) {
        float ov = __shfl_xor(v, off); int oi = __shfl_xor(i, off);
        if (better(ov, oi, v, i)) { v = ov; i = oi; }
      }
      if (t == 0) {
        lv[p] = __expf(v - M) / ps;
        lc[p] = i / NF;
        lf[p] = i % NF;
      }
      if (cii == i) cvv = -3.4e38f;
    }
  }
  __syncthreads();

#pragma unroll 2
  for (int half = 0; half < 2; half++) {
    const int n = chunk * 2048 + half * 1024 + t * 4;  // 4 samples per thread per half
    const int m = n - shift;              // shift is a multiple of 256 -> all 4 samples share frames
    float o[4] = {0.f, 0.f, 0.f, 0.f};
    if (m >= 0) {
      const int f1 = m >> 8;
      const int w1 = m & 255;
      float a[4] = {0.f, 0.f, 0.f, 0.f};
      float g[4] = {0.f, 0.f, 0.f, 0.f};
      const bool hasf2 = (f1 > 0);
#pragma unroll
      for (int k = 0; k < 8; k++) {
        const float v = lv[k];
        const int c = lc[k];
        const int d1 = f1 - lf[k];
        if (d1 >= 0 && d1 < TPROP) {
          const float4 q = *(const float4*)(R + ((size_t)(d1 * CPD + c)) * WSZ + w1);
          a[0] += v * q.x; a[1] += v * q.y; a[2] += v * q.z; a[3] += v * q.w;
        }
        if (d1 == 0) {
          const float4 q = *(const float4*)(P2 + (size_t)c * WSZ + w1);
          a[0] += v * q.x; a[1] += v * q.y; a[2] += v * q.z; a[3] += v * q.w;
        }
        if (hasf2) {
          const int d2 = d1 - 1;
          if (d2 >= 0 && d2 < TPROP) {
            const float4 q = *(const float4*)(R + ((size_t)(d2 * CPD + c)) * WSZ + w1 + 256);
            g[0] += v * q.x; g[1] += v * q.y; g[2] += v * q.z; g[3] += v * q.w;
          }
          if (d2 == 0) {
            const float4 q = *(const float4*)(P2 + (size_t)c * WSZ + w1 + 256);
            g[0] += v * q.x; g[1] += v * q.y; g[2] += v * q.z; g[3] += v * q.w;
          }
        }
      }
      const float k2pi = 6.283185307179586f / (float)WSZ;
#pragma unroll
      for (int i = 0; i < 4; i++) {
        const float cs = __cosf(k2pi * (float)(w1 + i));
        const float wa = 0.5f * (1.f - cs);
        const float wb = 0.5f * (1.f + cs);
        o[i] = wa * a[i] + wb * g[i];
      }
    }
    float4 ov = make_float4(o[0], o[1], o[2], o[3]);
    *(float4*)(out + (size_t)b * NSAMP + n) = ov;
  }
}

extern "C" void kernel_launch(void* const* d_in, const int* in_sizes, int n_in,
                              void* d_out, int out_size, void* d_ws, size_t ws_size,
                              hipStream_t stream) {
  const float* cpc    = (const float*)d_in[0];
  const float* times  = (const float*)d_in[1];
  const float* lookup = (const float*)d_in[2];
  const float* proj   = (const float*)d_in[3];
  const float* Amat   = (const float*)d_in[4];
  const float* Bmat   = (const float*)d_in[5];
  const float* Cmat   = (const float*)d_in[6];
  const float* Dmat   = (const float*)d_in[7];
  float* out = (float*)d_out;

  // ws floats: [1536 reserved] pshift[64] P2[32768] R[262144] [S region unused]
  //            pmax[512] psum[512] pcv[4096] pci[4096]
  float* w      = (float*)d_ws;
  int*   pshift = (int*)(w + 1536);
  float* P2     = w + 1600;
  float* R      = P2 + CPD * WSZ;
  float* S_unused = R + (size_t)TPROP * CPD * WSZ;
  float* pmax   = S_unused + (size_t)TPROP * CPD * SD;
  float* psum   = pmax + NBATCH * NSLICE;
  float* pcv    = psum + NBATCH * NSLICE;
  int*   pci    = (int*)(pcv + NBATCH * NSLICE * 8);

  hipLaunchKernelGGL(k_scan, dim3(CPD + NBATCH * NSLICE), dim3(256), 0, stream,
                     cpc, times, lookup, proj, Amat, Bmat, Cmat, Dmat,
                     P2, R, pmax, psum, pcv, pci, pshift);
  hipLaunchKernelGGL(k_out, dim3(NBATCH * 32), dim3(256), 0, stream,
                     pmax, psum, pcv, pci, pshift, P2, R, out);
}

// Round 7
// 120.443 us; speedup vs baseline: 8.3753x; 1.0390x over previous
//
#include <hip/hip_runtime.h>
#include <math.h>

#define NBATCH 64
#define NCP    512
#define CPD    64
#define NF     256
#define WSZ    512
#define SD     128
#define NSAMP  65536
#define TPROP  8   // ||A||~0.13/step -> truncation error ~1e-14 abs, threshold ~1e-8
#define NSLICE 8
#define SLICE_ELEMS 2048

// ---------------------------------------------------------------------------
// SESSION LEDGER (do not retry these):
//  r2: A in per-thread VGPR array -> compiler pinned VGPR=60, rematerialized loads
//      in the serial loop; k_scan 55-66us. REGRESSION.
//  r4: A staged in 64KB LDS -> +2.4us vs L2/L3 streaming. REGRESSION.
//  r5: single-kernel fusion with manual agent-scope spin barrier -> ~950us idle:
//      cross-XCD L2 non-coherence starves the spin. CATASTROPHIC. Never spin across XCDs.
//  r6: revert-best 125.1us; replay showed k_scan 47us, VALUBusy 9.5% -> chain blocks
//      are latency-idle on ~770 scalar strided loads/thread (L2 swept cold each iter
//      by the 2x256MiB harness fills; reads come from L3 ~700-1200cy).
//  r7 (this): float4-widened chain GEMVs -> 4x fewer latency batches. Same structure.
// ---------------------------------------------------------------------------

__device__ __forceinline__ bool better(float v1, int i1, float v2, int i2) {
  // value descending, index ascending tie-break (matches jax argmax/top_k)
  return (v1 > v2) || (v1 == v2 && i1 < i2);
}

__device__ __forceinline__ void cswap(float& v1, int& i1, float& v2, int& i2) {
  if (better(v2, i2, v1, i1)) {
    float tv = v1; v1 = v2; v2 = tv;
    int   ti = i1; i1 = i2; i2 = ti;
  }
}

__device__ __forceinline__ void wave_argmax(float& v, int& i) {
#pragma unroll
  for (int off = 32; off > 0; off >>= 1) {
    float ov = __shfl_down(v, off);
    int   oi = __shfl_down(i, off);
    if (better(ov, oi, v, i)) { v = ov; i = oi; }
  }
}

// merge this lane's sorted-desc 8-list with partner lane's (xor off); both keep top-8
__device__ __forceinline__ void xor_merge8(float* m, int* mi, int off) {
  float lb[8]; int ib8[8];
#pragma unroll
  for (int k = 0; k < 8; k++) { lb[k] = __shfl_xor(m[k], off); ib8[k] = __shfl_xor(mi[k], off); }
  float x[8]; int xi[8];
#pragma unroll
  for (int k = 0; k < 8; k++) {   // top half of merged 16 (bitonic)
    const bool ta = better(m[k], mi[k], lb[7 - k], ib8[7 - k]);
    x[k]  = ta ? m[k]  : lb[7 - k];
    xi[k] = ta ? mi[k] : ib8[7 - k];
  }
  // bitonic clean desc: strides 4,2,1
  cswap(x[0], xi[0], x[4], xi[4]); cswap(x[1], xi[1], x[5], xi[5]);
  cswap(x[2], xi[2], x[6], xi[6]); cswap(x[3], xi[3], x[7], xi[7]);
  cswap(x[0], xi[0], x[2], xi[2]); cswap(x[1], xi[1], x[3], xi[3]);
  cswap(x[4], xi[4], x[6], xi[6]); cswap(x[5], xi[5], x[7], xi[7]);
  cswap(x[0], xi[0], x[1], xi[1]); cswap(x[2], xi[2], x[3], xi[3]);
  cswap(x[4], xi[4], x[5], xi[5]); cswap(x[6], xi[6], x[7], xi[7]);
#pragma unroll
  for (int k = 0; k < 8; k++) { m[k] = x[k]; mi[k] = xi[k]; }
}

// ---------------- K1: blocks 0..63 = S-chain + R (longest pole, dispatched first);
//                     blocks 64..575 = (batch, slice) selection; first 256 also do a P2 quarter ----------------
__global__ __launch_bounds__(256) void k_scan(
    const float* __restrict__ cpc, const float* __restrict__ times,
    const float* __restrict__ lookup,
    const float* __restrict__ proj, const float* __restrict__ Amat,
    const float* __restrict__ Bmat, const float* __restrict__ Cmat,
    const float* __restrict__ Dmat,
    float* __restrict__ P2, float* __restrict__ R,
    float* __restrict__ pmax, float* __restrict__ psum,
    float* __restrict__ pcv, int* __restrict__ pci,
    int* __restrict__ pshift) {
  const int t = threadIdx.x;
  const int bid = blockIdx.x;

  // chain-path LDS
  __shared__ __align__(16) float sjall[SD * 8];   // 4 KB, [i][j] layout for float4 broadcast
  __shared__ __align__(16) float sred8[8 * SD];   // 4 KB, K-octant partials (float4-writes)
  __shared__ float sb[2][SD];
  __shared__ float sred[256];
  // slice-path LDS (small)
  __shared__ float wred[4];
  __shared__ int   wredi[4];
  __shared__ int   sRow;
  __shared__ float wlv[32];
  __shared__ int   wli[32];
  __shared__ float sSmax;

  if (bid < CPD) {
    // ----- S-chain: s_j = proj_c @ B @ A^j, then R[j,c,:] = s_j @ C -----
    // float4-widened GEMVs: thread owns 4 consecutive output columns; loads are
    // 16B each -> 4x fewer latency batches than the r6 scalar form (r6 replay:
    // 47us, VALUBusy 9.5% = latency-idle).
    const int c = bid;
    const int dg = t & 31;   // d-group: columns 4*dg .. 4*dg+3
    const int h  = t >> 5;   // K-octant

    // --- B-pass: s0[d] = sum_k p[k] * B[k][d], K split 8 ways ---
    {
      const float4* B4 = (const float4*)Bmat + dg;                     // + k*32 per row
      const float4* P4 = (const float4*)(proj + (size_t)c * WSZ + h * 64);
      float4 a0 = {0.f, 0.f, 0.f, 0.f}, a1 = a0, a2 = a0, a3 = a0;
#pragma unroll 4
      for (int kb = 0; kb < 64; kb += 4) {
        const float4 pv = P4[kb >> 2];
        const float4 q0 = B4[(size_t)(h * 64 + kb + 0) * 32];
        const float4 q1 = B4[(size_t)(h * 64 + kb + 1) * 32];
        const float4 q2 = B4[(size_t)(h * 64 + kb + 2) * 32];
        const float4 q3 = B4[(size_t)(h * 64 + kb + 3) * 32];
        a0.x = fmaf(pv.x, q0.x, a0.x); a0.y = fmaf(pv.x, q0.y, a0.y);
        a0.z = fmaf(pv.x, q0.z, a0.z); a0.w = fmaf(pv.x, q0.w, a0.w);
        a1.x = fmaf(pv.y, q1.x, a1.x); a1.y = fmaf(pv.y, q1.y, a1.y);
        a1.z = fmaf(pv.y, q1.z, a1.z); a1.w = fmaf(pv.y, q1.w, a1.w);
        a2.x = fmaf(pv.z, q2.x, a2.x); a2.y = fmaf(pv.z, q2.y, a2.y);
        a2.z = fmaf(pv.z, q2.z, a2.z); a2.w = fmaf(pv.z, q2.w, a2.w);
        a3.x = fmaf(pv.w, q3.x, a3.x); a3.y = fmaf(pv.w, q3.y, a3.y);
        a3.z = fmaf(pv.w, q3.z, a3.z); a3.w = fmaf(pv.w, q3.w, a3.w);
      }
      float4 s4;
      s4.x = (a0.x + a1.x) + (a2.x + a3.x);
      s4.y = (a0.y + a1.y) + (a2.y + a3.y);
      s4.z = (a0.z + a1.z) + (a2.z + a3.z);
      s4.w = (a0.w + a1.w) + (a2.w + a3.w);
      ((float4*)sred8)[h * 32 + dg] = s4;
    }
    __syncthreads();
    if (t < SD) {
      sb[0][t] = ((sred8[t] + sred8[SD + t]) + (sred8[2 * SD + t] + sred8[3 * SD + t]))
               + ((sred8[4 * SD + t] + sred8[5 * SD + t]) + (sred8[6 * SD + t] + sred8[7 * SD + t]));
    }
    __syncthreads();

    // --- j-loop: s' = s @ A, 16 float4 A-loads/thread/step (one latency batch) ---
    int cur = 0;
    const float4* A4 = (const float4*)Amat + dg;                       // + i*32 per row
    for (int j = 0; j < TPROP; j++) {
      if (t < SD) sjall[t * 8 + j] = sb[cur][t];
      float4 av = {0.f, 0.f, 0.f, 0.f}, bv = av;
      const float* sh = sb[cur] + h * 16;
#pragma unroll
      for (int i = 0; i < 16; i += 2) {
        const float s0v = sh[i], s1v = sh[i + 1];
        const float4 q0 = A4[(size_t)(h * 16 + i) * 32];
        const float4 q1 = A4[(size_t)(h * 16 + i + 1) * 32];
        av.x = fmaf(s0v, q0.x, av.x); av.y = fmaf(s0v, q0.y, av.y);
        av.z = fmaf(s0v, q0.z, av.z); av.w = fmaf(s0v, q0.w, av.w);
        bv.x = fmaf(s1v, q1.x, bv.x); bv.y = fmaf(s1v, q1.y, bv.y);
        bv.z = fmaf(s1v, q1.z, bv.z); bv.w = fmaf(s1v, q1.w, bv.w);
      }
      float4 s4;
      s4.x = av.x + bv.x; s4.y = av.y + bv.y; s4.z = av.z + bv.z; s4.w = av.w + bv.w;
      ((float4*)sred8)[h * 32 + dg] = s4;
      __syncthreads();
      if (t < SD) {
        sb[cur ^ 1][t] = ((sred8[t] + sred8[SD + t]) + (sred8[2 * SD + t] + sred8[3 * SD + t]))
                       + ((sred8[4 * SD + t] + sred8[5 * SD + t]) + (sred8[6 * SD + t] + sred8[7 * SD + t]));
      }
      __syncthreads();
      cur ^= 1;
    }

    // --- R pass: R[j,c,w] = sum_i s_j[i] * C[i][w]; thread = (w-group, j-half);
    //     no LDS reduce; i-sweep order identical to r6 (same arithmetic given s_j) ---
    {
      const int wg = t & 127;            // w-group: columns 4*wg .. 4*wg+3
      const int jh = (t >> 7) * 4;       // j base: 0 or 4
      float4 r4[4];
#pragma unroll
      for (int k = 0; k < 4; k++) r4[k] = make_float4(0.f, 0.f, 0.f, 0.f);
      const float4* C4 = (const float4*)Cmat + wg;                     // + i*128 per row
#pragma unroll 4
      for (int i = 0; i < SD; i++) {
        const float4 cv = C4[(size_t)i * 128];
        const float4 sj = *(const float4*)(sjall + i * 8 + jh);
        r4[0].x = fmaf(sj.x, cv.x, r4[0].x); r4[0].y = fmaf(sj.x, cv.y, r4[0].y);
        r4[0].z = fmaf(sj.x, cv.z, r4[0].z); r4[0].w = fmaf(sj.x, cv.w, r4[0].w);
        r4[1].x = fmaf(sj.y, cv.x, r4[1].x); r4[1].y = fmaf(sj.y, cv.y, r4[1].y);
        r4[1].z = fmaf(sj.y, cv.z, r4[1].z); r4[1].w = fmaf(sj.y, cv.w, r4[1].w);
        r4[2].x = fmaf(sj.z, cv.x, r4[2].x); r4[2].y = fmaf(sj.z, cv.y, r4[2].y);
        r4[2].z = fmaf(sj.z, cv.z, r4[2].z); r4[2].w = fmaf(sj.z, cv.w, r4[2].w);
        r4[3].x = fmaf(sj.w, cv.x, r4[3].x); r4[3].y = fmaf(sj.w, cv.y, r4[3].y);
        r4[3].z = fmaf(sj.w, cv.z, r4[3].z); r4[3].w = fmaf(sj.w, cv.w, r4[3].w);
      }
#pragma unroll
      for (int jj = 0; jj < 4; jj++)
        *(float4*)(R + ((size_t)((jh + jj) * CPD + c)) * WSZ + wg * 4) = r4[jj];
    }
    return;
  }

  const int sbid = bid - CPD;
  const int b = sbid >> 3, s = sbid & 7;
  const int lane = t & 63, wv = t >> 6;

  // --- cpc argmax (redundant across the 8 slice blocks; 2 KB, cheap) ---
  {
    float v0 = cpc[b * NCP + t];
    float v1 = cpc[b * NCP + t + 256];
    float bv = v0; int bi = t;
    if (better(v1, t + 256, bv, bi)) { bv = v1; bi = t + 256; }
    wave_argmax(bv, bi);
    if (lane == 0) { wred[wv] = bv; wredi[wv] = bi; }
    __syncthreads();
    if (t == 0) {
      float fv = wred[0]; int fi = wredi[0];
#pragma unroll
      for (int q = 1; q < 4; q++)
        if (better(wred[q], wredi[q], fv, fi)) { fv = wred[q]; fi = wredi[q]; }
      sRow = fi;
    }
    __syncthreads();
  }
  const float* row = lookup + (size_t)sRow * (CPD * NF);
  const float4* row4 = (const float4*)(row + s * SLICE_ELEMS);

  // --- load 8 elements (2 independent float4) ---
  const float4 va = row4[t];
  const float4 vb = row4[t + 256];
  const int gbase = s * SLICE_ELEMS;
  float ev[8] = {va.x, va.y, va.z, va.w, vb.x, vb.y, vb.z, vb.w};
  int   ei[8] = {gbase + t * 4,        gbase + t * 4 + 1,
                 gbase + t * 4 + 2,    gbase + t * 4 + 3,
                 gbase + 1024 + t * 4, gbase + 1024 + t * 4 + 1,
                 gbase + 1024 + t * 4 + 2, gbase + 1024 + t * 4 + 3};

  // --- per-thread sort desc (static bubble network, registers) ---
  float m[8]; int mi[8];
#pragma unroll
  for (int k = 0; k < 8; k++) { m[k] = ev[k]; mi[k] = ei[k]; }
#pragma unroll
  for (int i = 0; i < 7; i++)
#pragma unroll
    for (int j = 0; j < 7 - i; j++) cswap(m[j], mi[j], m[j + 1], mi[j + 1]);

  // --- wave-level merge: 6 shuffle rounds, no barriers, no LDS ---
  xor_merge8(m, mi, 1);  xor_merge8(m, mi, 2);  xor_merge8(m, mi, 4);
  xor_merge8(m, mi, 8);  xor_merge8(m, mi, 16); xor_merge8(m, mi, 32);

  if (lane < 8) { wlv[wv * 8 + lane] = m[lane]; wli[wv * 8 + lane] = mi[lane]; }
  __syncthreads();

  // --- wave 0: bitonic sort-32 of the 4 wave lists via shuffles ---
  if (wv == 0) {
    float v = (lane < 32) ? wlv[lane] : -3.4e38f;
    int   i = (lane < 32) ? wli[lane] : 0x7fffffff;
#pragma unroll
    for (int k = 2; k <= 32; k <<= 1) {
#pragma unroll
      for (int j = k >> 1; j > 0; j >>= 1) {
        const float pv = __shfl_xor(v, j);
        const int   pi = __shfl_xor(i, j);
        const bool keepBetter = (((lane & k) == 0) == ((lane & j) == 0));
        if (keepBetter == better(pv, pi, v, i)) { v = pv; i = pi; }
      }
    }
    if (lane == 0) sSmax = v;
    if (lane < 8) { pcv[b * 64 + s * 8 + lane] = v; pci[b * 64 + s * 8 + lane] = i; }
  }
  __syncthreads();
  const float smax = sSmax;

  // --- partial exp-sum (8 independent exps per thread) ---
  float se = 0.f;
#pragma unroll
  for (int k = 0; k < 8; k++) se += __expf(ev[k] - smax);
#pragma unroll
  for (int off = 32; off > 0; off >>= 1) se += __shfl_down(se, off);
  if (lane == 0) wred[wv] = se;
  __syncthreads();
  if (t == 0) {
    pmax[b * 8 + s] = smax;
    psum[b * 8 + s] = (wred[0] + wred[1]) + (wred[2] + wred[3]);
  }
  __syncthreads();  // protect wred against reuse below

  // --- dirac shift (slice 0 only): argmax over times[b,0,:256] ---
  if (s == 0) {
    float tv = times[b * NF + t]; int ti = t;
    wave_argmax(tv, ti);
    if (lane == 0) { wred[wv] = tv; wredi[wv] = ti; }
    __syncthreads();
    if (t == 0) {
      float fv = wred[0]; int fi = wredi[0];
#pragma unroll
      for (int q = 1; q < 4; q++)
        if (better(wred[q], wredi[q], fv, fi)) { fv = wred[q]; fi = wredi[q]; }
      pshift[b] = fi * (NSAMP / NF);
    }
  }

  // --- P2 quarter-row (first 256 slice blocks): P2[c, q*128 : q*128+128] = proj[c,:] @ D[:, cols] ---
  if (sbid < 256) {
    const int c2 = sbid >> 2, q = sbid & 3;
    const int col = q * 128 + (t & 127);
    const int uh = t >> 7;                      // K-split 2 over u
    const float* pr = proj + (size_t)c2 * WSZ + uh * 256;  // uniform -> scalar loads
    const float* Dp = Dmat + (size_t)(uh * 256) * WSZ + col;
    float a[8];
#pragma unroll
    for (int k = 0; k < 8; k++) a[k] = 0.f;
#pragma unroll 2
    for (int u = 0; u < 256; u += 8) {
#pragma unroll
      for (int v = 0; v < 8; v++)
        a[v] = fmaf(pr[u + v], Dp[(size_t)(u + v) * WSZ], a[v]);
    }
    float acc = 0.f;
#pragma unroll
    for (int k = 0; k < 8; k++) acc += a[k];
    sred[t] = acc;
    __syncthreads();
    if (t < 128) P2[(size_t)c2 * WSZ + q * 128 + t] = sred[t] + sred[t + 128];
  }
}

// ---------------- K2: per-block redundant top-8 combine (1 wave, deterministic) + output assembly ----------------
// 2048 blocks: 32 per batch, each covering 2048 samples (two float4 per thread)
__global__ __launch_bounds__(256) void k_out(
    const float* __restrict__ pmax, const float* __restrict__ psum,
    const float* __restrict__ pcv, const int* __restrict__ pci,
    const int* __restrict__ pshift,
    const float* __restrict__ P2, const float* __restrict__ R,
    float* __restrict__ out) {
  const int b = blockIdx.x >> 5;        // 32 blocks per batch
  const int chunk = blockIdx.x & 31;
  const int t = threadIdx.x;
  __shared__ float lv[8];
  __shared__ int   lc[8];
  __shared__ int   lf[8];

  const int shift = pshift[b];          // issue early: latency hides under the combine

  if (t < 64) {
    // merge 8 slice top-8 lists for batch b (identical in every block of this batch)
    const int sl = t >> 3;
    float M = pmax[b * 8 + sl];
#pragma unroll
    for (int off = 1; off < 64; off <<= 1) M = fmaxf(M, __shfl_xor(M, off));
    float ps = ((t & 7) == 0) ? psum[b * 8 + sl] * __expf(pmax[b * 8 + sl] - M) : 0.f;
#pragma unroll
    for (int off = 1; off < 64; off <<= 1) ps += __shfl_xor(ps, off);
    float cvv = pcv[b * 64 + t]; int cii = pci[b * 64 + t];
    for (int p = 0; p < 8; p++) {
      float v = cvv; int i = cii;
#pragma unroll
      for (int off = 1; off < 64; off <<= 1) {
        float ov = __shfl_xor(v, off); int oi = __shfl_xor(i, off);
        if (better(ov, oi, v, i)) { v = ov; i = oi; }
      }
      if (t == 0) {
        lv[p] = __expf(v - M) / ps;
        lc[p] = i / NF;
        lf[p] = i % NF;
      }
      if (cii == i) cvv = -3.4e38f;
    }
  }
  __syncthreads();

#pragma unroll 2
  for (int half = 0; half < 2; half++) {
    const int n = chunk * 2048 + half * 1024 + t * 4;  // 4 samples per thread per half
    const int m = n - shift;              // shift is a multiple of 256 -> all 4 samples share frames
    float o[4] = {0.f, 0.f, 0.f, 0.f};
    if (m >= 0) {
      const int f1 = m >> 8;
      const int w1 = m & 255;
      float a[4] = {0.f, 0.f, 0.f, 0.f};
      float g[4] = {0.f, 0.f, 0.f, 0.f};
      const bool hasf2 = (f1 > 0);
#pragma unroll
      for (int k = 0; k < 8; k++) {
        const float v = lv[k];
        const int c = lc[k];
        const int d1 = f1 - lf[k];
        if (d1 >= 0 && d1 < TPROP) {
          const float4 q = *(const float4*)(R + ((size_t)(d1 * CPD + c)) * WSZ + w1);
          a[0] += v * q.x; a[1] += v * q.y; a[2] += v * q.z; a[3] += v * q.w;
        }
        if (d1 == 0) {
          const float4 q = *(const float4*)(P2 + (size_t)c * WSZ + w1);
          a[0] += v * q.x; a[1] += v * q.y; a[2] += v * q.z; a[3] += v * q.w;
        }
        if (hasf2) {
          const int d2 = d1 - 1;
          if (d2 >= 0 && d2 < TPROP) {
            const float4 q = *(const float4*)(R + ((size_t)(d2 * CPD + c)) * WSZ + w1 + 256);
            g[0] += v * q.x; g[1] += v * q.y; g[2] += v * q.z; g[3] += v * q.w;
          }
          if (d2 == 0) {
            const float4 q = *(const float4*)(P2 + (size_t)c * WSZ + w1 + 256);
            g[0] += v * q.x; g[1] += v * q.y; g[2] += v * q.z; g[3] += v * q.w;
          }
        }
      }
      const float k2pi = 6.283185307179586f / (float)WSZ;
#pragma unroll
      for (int i = 0; i < 4; i++) {
        const float cs = __cosf(k2pi * (float)(w1 + i));
        const float wa = 0.5f * (1.f - cs);
        const float wb = 0.5f * (1.f + cs);
        o[i] = wa * a[i] + wb * g[i];
      }
    }
    float4 ov = make_float4(o[0], o[1], o[2], o[3]);
    *(float4*)(out + (size_t)b * NSAMP + n) = ov;
  }
}

extern "C" void kernel_launch(void* const* d_in, const int* in_sizes, int n_in,
                              void* d_out, int out_size, void* d_ws, size_t ws_size,
                              hipStream_t stream) {
  const float* cpc    = (const float*)d_in[0];
  const float* times  = (const float*)d_in[1];
  const float* lookup = (const float*)d_in[2];
  const float* proj   = (const float*)d_in[3];
  const float* Amat   = (const float*)d_in[4];
  const float* Bmat   = (const float*)d_in[5];
  const float* Cmat   = (const float*)d_in[6];
  const float* Dmat   = (const float*)d_in[7];
  float* out = (float*)d_out;

  // ws floats: [1536 reserved] pshift[64] P2[32768] R[262144] [S region unused]
  //            pmax[512] psum[512] pcv[4096] pci[4096]
  float* w      = (float*)d_ws;
  int*   pshift = (int*)(w + 1536);
  float* P2     = w + 1600;
  float* R      = P2 + CPD * WSZ;
  float* S_unused = R + (size_t)TPROP * CPD * WSZ;
  float* pmax   = S_unused + (size_t)TPROP * CPD * SD;
  float* psum   = pmax + NBATCH * NSLICE;
  float* pcv    = psum + NBATCH * NSLICE;
  int*   pci    = (int*)(pcv + NBATCH * NSLICE * 8);

  hipLaunchKernelGGL(k_scan, dim3(CPD + NBATCH * NSLICE), dim3(256), 0, stream,
                     cpc, times, lookup, proj, Amat, Bmat, Cmat, Dmat,
                     P2, R, pmax, psum, pcv, pci, pshift);
  hipLaunchKernelGGL(k_out, dim3(NBATCH * 32), dim3(256), 0, stream,
                     pmax, psum, pcv, pci, pshift, P2, R, out);
}

// Round 8
// 118.600 us; speedup vs baseline: 8.5054x; 1.0155x over previous
//
#include <hip/hip_runtime.h>
#include <math.h>

#define NBATCH 64
#define NCP    512
#define CPD    64
#define NF     256
#define WSZ    512
#define SD     128
#define NSAMP  65536
#define TPROP  8   // ||A||~0.13/step -> truncation error ~1e-14 abs, threshold ~1e-8
#define NSLICE 8
#define SLICE_ELEMS 2048

// ---------------------------------------------------------------------------
// SESSION LEDGER (do not retry these):
//  r2: A in per-thread VGPR array -> VGPR=60 remat pathology; k_scan 55-66us. REGRESSION.
//  r4: A staged in 64KB LDS -> +2.4us vs L2/L3 streaming. REGRESSION.
//  r5: manual agent-scope spin barrier -> ~950us (cross-XCD L2 non-coherence starves
//      the spin). CATASTROPHIC. Never spin across XCDs.
//  r6: scalar strided chain loads -> k_scan 47us replay, VALUBusy 9.5% (latency-idle).
//  r7: float4-widened chain GEMVs -> 125.1 -> 120.4us. PROVEN LEVER: widen scalar
//      strided GEMV loads to float4 (4x fewer latency batches).
//  r8 (this): same lever on P2 path (was 256 scalar stride-2048B loads/thread);
//      + k_out early-exit for blocks entirely below the impulse shift (~half of
//      all blocks skip the ~600cy combine and just write zeros).
// ---------------------------------------------------------------------------

__device__ __forceinline__ bool better(float v1, int i1, float v2, int i2) {
  // value descending, index ascending tie-break (matches jax argmax/top_k)
  return (v1 > v2) || (v1 == v2 && i1 < i2);
}

__device__ __forceinline__ void cswap(float& v1, int& i1, float& v2, int& i2) {
  if (better(v2, i2, v1, i1)) {
    float tv = v1; v1 = v2; v2 = tv;
    int   ti = i1; i1 = i2; i2 = ti;
  }
}

__device__ __forceinline__ void wave_argmax(float& v, int& i) {
#pragma unroll
  for (int off = 32; off > 0; off >>= 1) {
    float ov = __shfl_down(v, off);
    int   oi = __shfl_down(i, off);
    if (better(ov, oi, v, i)) { v = ov; i = oi; }
  }
}

// merge this lane's sorted-desc 8-list with partner lane's (xor off); both keep top-8
__device__ __forceinline__ void xor_merge8(float* m, int* mi, int off) {
  float lb[8]; int ib8[8];
#pragma unroll
  for (int k = 0; k < 8; k++) { lb[k] = __shfl_xor(m[k], off); ib8[k] = __shfl_xor(mi[k], off); }
  float x[8]; int xi[8];
#pragma unroll
  for (int k = 0; k < 8; k++) {   // top half of merged 16 (bitonic)
    const bool ta = better(m[k], mi[k], lb[7 - k], ib8[7 - k]);
    x[k]  = ta ? m[k]  : lb[7 - k];
    xi[k] = ta ? mi[k] : ib8[7 - k];
  }
  // bitonic clean desc: strides 4,2,1
  cswap(x[0], xi[0], x[4], xi[4]); cswap(x[1], xi[1], x[5], xi[5]);
  cswap(x[2], xi[2], x[6], xi[6]); cswap(x[3], xi[3], x[7], xi[7]);
  cswap(x[0], xi[0], x[2], xi[2]); cswap(x[1], xi[1], x[3], xi[3]);
  cswap(x[4], xi[4], x[6], xi[6]); cswap(x[5], xi[5], x[7], xi[7]);
  cswap(x[0], xi[0], x[1], xi[1]); cswap(x[2], xi[2], x[3], xi[3]);
  cswap(x[4], xi[4], x[5], xi[5]); cswap(x[6], xi[6], x[7], xi[7]);
#pragma unroll
  for (int k = 0; k < 8; k++) { m[k] = x[k]; mi[k] = xi[k]; }
}

// ---------------- K1: blocks 0..63 = S-chain + R (longest pole, dispatched first);
//                     blocks 64..575 = (batch, slice) selection; first 256 also do a P2 quarter ----------------
__global__ __launch_bounds__(256) void k_scan(
    const float* __restrict__ cpc, const float* __restrict__ times,
    const float* __restrict__ lookup,
    const float* __restrict__ proj, const float* __restrict__ Amat,
    const float* __restrict__ Bmat, const float* __restrict__ Cmat,
    const float* __restrict__ Dmat,
    float* __restrict__ P2, float* __restrict__ R,
    float* __restrict__ pmax, float* __restrict__ psum,
    float* __restrict__ pcv, int* __restrict__ pci,
    int* __restrict__ pshift) {
  const int t = threadIdx.x;
  const int bid = blockIdx.x;

  // chain-path LDS (sred8 is reused by the slice path's P2 reduction)
  __shared__ __align__(16) float sjall[SD * 8];   // 4 KB, [i][j] layout for float4 broadcast
  __shared__ __align__(16) float sred8[8 * SD];   // 4 KB, K-octant partials (float4-writes)
  __shared__ float sb[2][SD];
  // slice-path LDS (small)
  __shared__ float wred[4];
  __shared__ int   wredi[4];
  __shared__ int   sRow;
  __shared__ float wlv[32];
  __shared__ int   wli[32];
  __shared__ float sSmax;

  if (bid < CPD) {
    // ----- S-chain: s_j = proj_c @ B @ A^j, then R[j,c,:] = s_j @ C -----
    // float4-widened GEMVs (r7 proven lever).
    const int c = bid;
    const int dg = t & 31;   // d-group: columns 4*dg .. 4*dg+3
    const int h  = t >> 5;   // K-octant

    // --- B-pass: s0[d] = sum_k p[k] * B[k][d], K split 8 ways ---
    {
      const float4* B4 = (const float4*)Bmat + dg;                     // + k*32 per row
      const float4* P4 = (const float4*)(proj + (size_t)c * WSZ + h * 64);
      float4 a0 = {0.f, 0.f, 0.f, 0.f}, a1 = a0, a2 = a0, a3 = a0;
#pragma unroll 4
      for (int kb = 0; kb < 64; kb += 4) {
        const float4 pv = P4[kb >> 2];
        const float4 q0 = B4[(size_t)(h * 64 + kb + 0) * 32];
        const float4 q1 = B4[(size_t)(h * 64 + kb + 1) * 32];
        const float4 q2 = B4[(size_t)(h * 64 + kb + 2) * 32];
        const float4 q3 = B4[(size_t)(h * 64 + kb + 3) * 32];
        a0.x = fmaf(pv.x, q0.x, a0.x); a0.y = fmaf(pv.x, q0.y, a0.y);
        a0.z = fmaf(pv.x, q0.z, a0.z); a0.w = fmaf(pv.x, q0.w, a0.w);
        a1.x = fmaf(pv.y, q1.x, a1.x); a1.y = fmaf(pv.y, q1.y, a1.y);
        a1.z = fmaf(pv.y, q1.z, a1.z); a1.w = fmaf(pv.y, q1.w, a1.w);
        a2.x = fmaf(pv.z, q2.x, a2.x); a2.y = fmaf(pv.z, q2.y, a2.y);
        a2.z = fmaf(pv.z, q2.z, a2.z); a2.w = fmaf(pv.z, q2.w, a2.w);
        a3.x = fmaf(pv.w, q3.x, a3.x); a3.y = fmaf(pv.w, q3.y, a3.y);
        a3.z = fmaf(pv.w, q3.z, a3.z); a3.w = fmaf(pv.w, q3.w, a3.w);
      }
      float4 s4;
      s4.x = (a0.x + a1.x) + (a2.x + a3.x);
      s4.y = (a0.y + a1.y) + (a2.y + a3.y);
      s4.z = (a0.z + a1.z) + (a2.z + a3.z);
      s4.w = (a0.w + a1.w) + (a2.w + a3.w);
      ((float4*)sred8)[h * 32 + dg] = s4;
    }
    __syncthreads();
    if (t < SD) {
      sb[0][t] = ((sred8[t] + sred8[SD + t]) + (sred8[2 * SD + t] + sred8[3 * SD + t]))
               + ((sred8[4 * SD + t] + sred8[5 * SD + t]) + (sred8[6 * SD + t] + sred8[7 * SD + t]));
    }
    __syncthreads();

    // --- j-loop: s' = s @ A, 16 float4 A-loads/thread/step (one latency batch) ---
    int cur = 0;
    const float4* A4 = (const float4*)Amat + dg;                       // + i*32 per row
    for (int j = 0; j < TPROP; j++) {
      if (t < SD) sjall[t * 8 + j] = sb[cur][t];
      float4 av = {0.f, 0.f, 0.f, 0.f}, bv = av;
      const float* sh = sb[cur] + h * 16;
#pragma unroll
      for (int i = 0; i < 16; i += 2) {
        const float s0v = sh[i], s1v = sh[i + 1];
        const float4 q0 = A4[(size_t)(h * 16 + i) * 32];
        const float4 q1 = A4[(size_t)(h * 16 + i + 1) * 32];
        av.x = fmaf(s0v, q0.x, av.x); av.y = fmaf(s0v, q0.y, av.y);
        av.z = fmaf(s0v, q0.z, av.z); av.w = fmaf(s0v, q0.w, av.w);
        bv.x = fmaf(s1v, q1.x, bv.x); bv.y = fmaf(s1v, q1.y, bv.y);
        bv.z = fmaf(s1v, q1.z, bv.z); bv.w = fmaf(s1v, q1.w, bv.w);
      }
      float4 s4;
      s4.x = av.x + bv.x; s4.y = av.y + bv.y; s4.z = av.z + bv.z; s4.w = av.w + bv.w;
      ((float4*)sred8)[h * 32 + dg] = s4;
      __syncthreads();
      if (t < SD) {
        sb[cur ^ 1][t] = ((sred8[t] + sred8[SD + t]) + (sred8[2 * SD + t] + sred8[3 * SD + t]))
                       + ((sred8[4 * SD + t] + sred8[5 * SD + t]) + (sred8[6 * SD + t] + sred8[7 * SD + t]));
      }
      __syncthreads();
      cur ^= 1;
    }

    // --- R pass: R[j,c,w] = sum_i s_j[i] * C[i][w]; thread = (w-group, j-half) ---
    {
      const int wg = t & 127;            // w-group: columns 4*wg .. 4*wg+3
      const int jh = (t >> 7) * 4;       // j base: 0 or 4
      float4 r4[4];
#pragma unroll
      for (int k = 0; k < 4; k++) r4[k] = make_float4(0.f, 0.f, 0.f, 0.f);
      const float4* C4 = (const float4*)Cmat + wg;                     // + i*128 per row
#pragma unroll 4
      for (int i = 0; i < SD; i++) {
        const float4 cv = C4[(size_t)i * 128];
        const float4 sj = *(const float4*)(sjall + i * 8 + jh);
        r4[0].x = fmaf(sj.x, cv.x, r4[0].x); r4[0].y = fmaf(sj.x, cv.y, r4[0].y);
        r4[0].z = fmaf(sj.x, cv.z, r4[0].z); r4[0].w = fmaf(sj.x, cv.w, r4[0].w);
        r4[1].x = fmaf(sj.y, cv.x, r4[1].x); r4[1].y = fmaf(sj.y, cv.y, r4[1].y);
        r4[1].z = fmaf(sj.y, cv.z, r4[1].z); r4[1].w = fmaf(sj.y, cv.w, r4[1].w);
        r4[2].x = fmaf(sj.z, cv.x, r4[2].x); r4[2].y = fmaf(sj.z, cv.y, r4[2].y);
        r4[2].z = fmaf(sj.z, cv.z, r4[2].z); r4[2].w = fmaf(sj.z, cv.w, r4[2].w);
        r4[3].x = fmaf(sj.w, cv.x, r4[3].x); r4[3].y = fmaf(sj.w, cv.y, r4[3].y);
        r4[3].z = fmaf(sj.w, cv.z, r4[3].z); r4[3].w = fmaf(sj.w, cv.w, r4[3].w);
      }
#pragma unroll
      for (int jj = 0; jj < 4; jj++)
        *(float4*)(R + ((size_t)((jh + jj) * CPD + c)) * WSZ + wg * 4) = r4[jj];
    }
    return;
  }

  const int sbid = bid - CPD;
  const int b = sbid >> 3, s = sbid & 7;
  const int lane = t & 63, wv = t >> 6;

  // --- cpc argmax (redundant across the 8 slice blocks; 2 KB, cheap) ---
  {
    float v0 = cpc[b * NCP + t];
    float v1 = cpc[b * NCP + t + 256];
    float bv = v0; int bi = t;
    if (better(v1, t + 256, bv, bi)) { bv = v1; bi = t + 256; }
    wave_argmax(bv, bi);
    if (lane == 0) { wred[wv] = bv; wredi[wv] = bi; }
    __syncthreads();
    if (t == 0) {
      float fv = wred[0]; int fi = wredi[0];
#pragma unroll
      for (int q = 1; q < 4; q++)
        if (better(wred[q], wredi[q], fv, fi)) { fv = wred[q]; fi = wredi[q]; }
      sRow = fi;
    }
    __syncthreads();
  }
  const float* row = lookup + (size_t)sRow * (CPD * NF);
  const float4* row4 = (const float4*)(row + s * SLICE_ELEMS);

  // --- load 8 elements (2 independent float4) ---
  const float4 va = row4[t];
  const float4 vb = row4[t + 256];
  const int gbase = s * SLICE_ELEMS;
  float ev[8] = {va.x, va.y, va.z, va.w, vb.x, vb.y, vb.z, vb.w};
  int   ei[8] = {gbase + t * 4,        gbase + t * 4 + 1,
                 gbase + t * 4 + 2,    gbase + t * 4 + 3,
                 gbase + 1024 + t * 4, gbase + 1024 + t * 4 + 1,
                 gbase + 1024 + t * 4 + 2, gbase + 1024 + t * 4 + 3};

  // --- per-thread sort desc (static bubble network, registers) ---
  float m[8]; int mi[8];
#pragma unroll
  for (int k = 0; k < 8; k++) { m[k] = ev[k]; mi[k] = ei[k]; }
#pragma unroll
  for (int i = 0; i < 7; i++)
#pragma unroll
    for (int j = 0; j < 7 - i; j++) cswap(m[j], mi[j], m[j + 1], mi[j + 1]);

  // --- wave-level merge: 6 shuffle rounds, no barriers, no LDS ---
  xor_merge8(m, mi, 1);  xor_merge8(m, mi, 2);  xor_merge8(m, mi, 4);
  xor_merge8(m, mi, 8);  xor_merge8(m, mi, 16); xor_merge8(m, mi, 32);

  if (lane < 8) { wlv[wv * 8 + lane] = m[lane]; wli[wv * 8 + lane] = mi[lane]; }
  __syncthreads();

  // --- wave 0: bitonic sort-32 of the 4 wave lists via shuffles ---
  if (wv == 0) {
    float v = (lane < 32) ? wlv[lane] : -3.4e38f;
    int   i = (lane < 32) ? wli[lane] : 0x7fffffff;
#pragma unroll
    for (int k = 2; k <= 32; k <<= 1) {
#pragma unroll
      for (int j = k >> 1; j > 0; j >>= 1) {
        const float pv = __shfl_xor(v, j);
        const int   pi = __shfl_xor(i, j);
        const bool keepBetter = (((lane & k) == 0) == ((lane & j) == 0));
        if (keepBetter == better(pv, pi, v, i)) { v = pv; i = pi; }
      }
    }
    if (lane == 0) sSmax = v;
    if (lane < 8) { pcv[b * 64 + s * 8 + lane] = v; pci[b * 64 + s * 8 + lane] = i; }
  }
  __syncthreads();
  const float smax = sSmax;

  // --- partial exp-sum (8 independent exps per thread) ---
  float se = 0.f;
#pragma unroll
  for (int k = 0; k < 8; k++) se += __expf(ev[k] - smax);
#pragma unroll
  for (int off = 32; off > 0; off >>= 1) se += __shfl_down(se, off);
  if (lane == 0) wred[wv] = se;
  __syncthreads();
  if (t == 0) {
    pmax[b * 8 + s] = smax;
    psum[b * 8 + s] = (wred[0] + wred[1]) + (wred[2] + wred[3]);
  }
  __syncthreads();  // protect wred against reuse below

  // --- dirac shift (slice 0 only): argmax over times[b,0,:256] ---
  if (s == 0) {
    float tv = times[b * NF + t]; int ti = t;
    wave_argmax(tv, ti);
    if (lane == 0) { wred[wv] = tv; wredi[wv] = ti; }
    __syncthreads();
    if (t == 0) {
      float fv = wred[0]; int fi = wredi[0];
#pragma unroll
      for (int q = 1; q < 4; q++)
        if (better(wred[q], wredi[q], fv, fi)) { fv = wred[q]; fi = wredi[q]; }
      pshift[b] = fi * (NSAMP / NF);
    }
  }

  // --- P2 quarter-row (first 256 slice blocks): P2[c2, q*128 : +128] = proj[c2,:] @ D[:, cols]
  //     float4-widened (r7/r8 lever): 64 float4 D-loads/thread vs 256 scalar; 8-way K-split
  //     reduced through sred8 (reused from the chain path's LDS). ---
  if (sbid < 256) {
    const int c2 = sbid >> 2, q = sbid & 3;
    const int cg = t & 31;   // col-group within the 128-col quarter: cols 4*cg .. 4*cg+3
    const int uh = t >> 5;   // K-octant: rows uh*64 .. uh*64+63
    const float4* D4 = (const float4*)Dmat + q * 32 + cg;              // + u*128 per row
    const float4* P4 = (const float4*)(proj + (size_t)c2 * WSZ + uh * 64);
    float4 a0 = {0.f, 0.f, 0.f, 0.f}, a1 = a0, a2 = a0, a3 = a0;
#pragma unroll 4
    for (int ub = 0; ub < 64; ub += 4) {
      const float4 pv = P4[ub >> 2];
      const float4 q0 = D4[(size_t)(uh * 64 + ub + 0) * 128];
      const float4 q1 = D4[(size_t)(uh * 64 + ub + 1) * 128];
      const float4 q2 = D4[(size_t)(uh * 64 + ub + 2) * 128];
      const float4 q3 = D4[(size_t)(uh * 64 + ub + 3) * 128];
      a0.x = fmaf(pv.x, q0.x, a0.x); a0.y = fmaf(pv.x, q0.y, a0.y);
      a0.z = fmaf(pv.x, q0.z, a0.z); a0.w = fmaf(pv.x, q0.w, a0.w);
      a1.x = fmaf(pv.y, q1.x, a1.x); a1.y = fmaf(pv.y, q1.y, a1.y);
      a1.z = fmaf(pv.y, q1.z, a1.z); a1.w = fmaf(pv.y, q1.w, a1.w);
      a2.x = fmaf(pv.z, q2.x, a2.x); a2.y = fmaf(pv.z, q2.y, a2.y);
      a2.z = fmaf(pv.z, q2.z, a2.z); a2.w = fmaf(pv.z, q2.w, a2.w);
      a3.x = fmaf(pv.w, q3.x, a3.x); a3.y = fmaf(pv.w, q3.y, a3.y);
      a3.z = fmaf(pv.w, q3.z, a3.z); a3.w = fmaf(pv.w, q3.w, a3.w);
    }
    float4 s4;
    s4.x = (a0.x + a1.x) + (a2.x + a3.x);
    s4.y = (a0.y + a1.y) + (a2.y + a3.y);
    s4.z = (a0.z + a1.z) + (a2.z + a3.z);
    s4.w = (a0.w + a1.w) + (a2.w + a3.w);
    ((float4*)sred8)[uh * 32 + cg] = s4;
    __syncthreads();
    if (t < 128) {
      const float r = ((sred8[t] + sred8[128 + t]) + (sred8[256 + t] + sred8[384 + t]))
                    + ((sred8[512 + t] + sred8[640 + t]) + (sred8[768 + t] + sred8[896 + t]));
      P2[(size_t)c2 * WSZ + q * 128 + t] = r;
    }
  }
}

// ---------------- K2: per-block redundant top-8 combine (1 wave, deterministic) + output assembly ----------------
// 2048 blocks: 32 per batch, each covering 2048 samples (two float4 per thread)
__global__ __launch_bounds__(256) void k_out(
    const float* __restrict__ pmax, const float* __restrict__ psum,
    const float* __restrict__ pcv, const int* __restrict__ pci,
    const int* __restrict__ pshift,
    const float* __restrict__ P2, const float* __restrict__ R,
    float* __restrict__ out) {
  const int b = blockIdx.x >> 5;        // 32 blocks per batch
  const int chunk = blockIdx.x & 31;
  const int t = threadIdx.x;
  __shared__ float lv[8];
  __shared__ int   lc[8];
  __shared__ int   lf[8];

  const int shift = pshift[b];          // issue early: latency hides under the combine

  // Early exit: out[n] = samples[n-shift], zero for n < shift. If this block's whole
  // 2048-sample range is below shift (avg ~half of all blocks for random times),
  // skip the ~600cy combine + gathers entirely. shift is block-uniform -> safe return.
  if (chunk * 2048 + 2047 < shift) {
    const float4 z = make_float4(0.f, 0.f, 0.f, 0.f);
    float* ob = out + (size_t)b * NSAMP + chunk * 2048;
    *(float4*)(ob + t * 4) = z;
    *(float4*)(ob + 1024 + t * 4) = z;
    return;
  }

  if (t < 64) {
    // merge 8 slice top-8 lists for batch b (identical in every block of this batch)
    const int sl = t >> 3;
    float M = pmax[b * 8 + sl];
#pragma unroll
    for (int off = 1; off < 64; off <<= 1) M = fmaxf(M, __shfl_xor(M, off));
    float ps = ((t & 7) == 0) ? psum[b * 8 + sl] * __expf(pmax[b * 8 + sl] - M) : 0.f;
#pragma unroll
    for (int off = 1; off < 64; off <<= 1) ps += __shfl_xor(ps, off);
    float cvv = pcv[b * 64 + t]; int cii = pci[b * 64 + t];
    for (int p = 0; p < 8; p++) {
      float v = cvv; int i = cii;
#pragma unroll
      for (int off = 1; off < 64; off <<= 1) {
        float ov = __shfl_xor(v, off); int oi = __shfl_xor(i, off);
        if (better(ov, oi, v, i)) { v = ov; i = oi; }
      }
      if (t == 0) {
        lv[p] = __expf(v - M) / ps;
        lc[p] = i / NF;
        lf[p] = i % NF;
      }
      if (cii == i) cvv = -3.4e38f;
    }
  }
  __syncthreads();

#pragma unroll 2
  for (int half = 0; half < 2; half++) {
    const int n = chunk * 2048 + half * 1024 + t * 4;  // 4 samples per thread per half
    const int m = n - shift;              // shift is a multiple of 256 -> all 4 samples share frames
    float o[4] = {0.f, 0.f, 0.f, 0.f};
    if (m >= 0) {
      const int f1 = m >> 8;
      const int w1 = m & 255;
      float a[4] = {0.f, 0.f, 0.f, 0.f};
      float g[4] = {0.f, 0.f, 0.f, 0.f};
      const bool hasf2 = (f1 > 0);
#pragma unroll
      for (int k = 0; k < 8; k++) {
        const float v = lv[k];
        const int c = lc[k];
        const int d1 = f1 - lf[k];
        if (d1 >= 0 && d1 < TPROP) {
          const float4 q = *(const float4*)(R + ((size_t)(d1 * CPD + c)) * WSZ + w1);
          a[0] += v * q.x; a[1] += v * q.y; a[2] += v * q.z; a[3] += v * q.w;
        }
        if (d1 == 0) {
          const float4 q = *(const float4*)(P2 + (size_t)c * WSZ + w1);
          a[0] += v * q.x; a[1] += v * q.y; a[2] += v * q.z; a[3] += v * q.w;
        }
        if (hasf2) {
          const int d2 = d1 - 1;
          if (d2 >= 0 && d2 < TPROP) {
            const float4 q = *(const float4*)(R + ((size_t)(d2 * CPD + c)) * WSZ + w1 + 256);
            g[0] += v * q.x; g[1] += v * q.y; g[2] += v * q.z; g[3] += v * q.w;
          }
          if (d2 == 0) {
            const float4 q = *(const float4*)(P2 + (size_t)c * WSZ + w1 + 256);
            g[0] += v * q.x; g[1] += v * q.y; g[2] += v * q.z; g[3] += v * q.w;
          }
        }
      }
      const float k2pi = 6.283185307179586f / (float)WSZ;
#pragma unroll
      for (int i = 0; i < 4; i++) {
        const float cs = __cosf(k2pi * (float)(w1 + i));
        const float wa = 0.5f * (1.f - cs);
        const float wb = 0.5f * (1.f + cs);
        o[i] = wa * a[i] + wb * g[i];
      }
    }
    float4 ov = make_float4(o[0], o[1], o[2], o[3]);
    *(float4*)(out + (size_t)b * NSAMP + n) = ov;
  }
}

extern "C" void kernel_launch(void* const* d_in, const int* in_sizes, int n_in,
                              void* d_out, int out_size, void* d_ws, size_t ws_size,
                              hipStream_t stream) {
  const float* cpc    = (const float*)d_in[0];
  const float* times  = (const float*)d_in[1];
  const float* lookup = (const float*)d_in[2];
  const float* proj   = (const float*)d_in[3];
  const float* Amat   = (const float*)d_in[4];
  const float* Bmat   = (const float*)d_in[5];
  const float* Cmat   = (const float*)d_in[6];
  const float* Dmat   = (const float*)d_in[7];
  float* out = (float*)d_out;

  // ws floats: [1536 reserved] pshift[64] P2[32768] R[262144] [S region unused]
  //            pmax[512] psum[512] pcv[4096] pci[4096]
  float* w      = (float*)d_ws;
  int*   pshift = (int*)(w + 1536);
  float* P2     = w + 1600;
  float* R      = P2 + CPD * WSZ;
  float* S_unused = R + (size_t)TPROP * CPD * WSZ;
  float* pmax   = S_unused + (size_t)TPROP * CPD * SD;
  float* psum   = pmax + NBATCH * NSLICE;
  float* pcv    = psum + NBATCH * NSLICE;
  int*   pci    = (int*)(pcv + NBATCH * NSLICE * 8);

  hipLaunchKernelGGL(k_scan, dim3(CPD + NBATCH * NSLICE), dim3(256), 0, stream,
                     cpc, times, lookup, proj, Amat, Bmat, Cmat, Dmat,
                     P2, R, pmax, psum, pcv, pci, pshift);
  hipLaunchKernelGGL(k_out, dim3(NBATCH * 32), dim3(256), 0, stream,
                     pmax, psum, pcv, pci, pshift, P2, R, out);
}

// Round 10
// 118.275 us; speedup vs baseline: 8.5288x; 1.0027x over previous
//
#include <hip/hip_runtime.h>
#include <math.h>

#define NBATCH 64
#define NCP    512
#define CPD    64
#define NF     256
#define WSZ    512
#define SD     128
#define NSAMP  65536
#define TPROP  8   // ||A||~0.13/step -> truncation error ~1e-14 abs, threshold ~1e-8
#define NSLICE 8
#define SLICE_ELEMS 2048

// ---------------------------------------------------------------------------
// SESSION LEDGER (do not retry these):
//  r2: A in per-thread VGPR array -> VGPR=60 remat pathology; k_scan 55-66us. REGRESSION.
//  r4: A staged in 64KB LDS -> +2.4us vs L2/L3 streaming. REGRESSION.
//  r5: manual agent-scope spin barrier -> ~950us (cross-XCD L2 non-coherence starves
//      the spin). CATASTROPHIC. Never spin across XCDs.
//  r6: scalar strided chain loads -> k_scan 47us replay, VALUBusy 9.5% (latency-idle).
//  r7: float4-widened chain GEMVs -> 125.1 -> 120.4us. PROVEN LEVER: widen scalar
//      strided GEMV loads to float4 (4x fewer latency batches).
//  r8: P2 float4-widened + k_out early-exit below shift -> 118.6us.
//  r9: R-pass unroll 4 -> 16 (16 C-loads in flight, 32 -> 8 serial latency batches).
//      UNTESTED: round-9 bench failed on container acquisition (infra, not kernel).
//  r10 (this): identical resubmit of r9.
// ---------------------------------------------------------------------------

__device__ __forceinline__ bool better(float v1, int i1, float v2, int i2) {
  // value descending, index ascending tie-break (matches jax argmax/top_k)
  return (v1 > v2) || (v1 == v2 && i1 < i2);
}

__device__ __forceinline__ void cswap(float& v1, int& i1, float& v2, int& i2) {
  if (better(v2, i2, v1, i1)) {
    float tv = v1; v1 = v2; v2 = tv;
    int   ti = i1; i1 = i2; i2 = ti;
  }
}

__device__ __forceinline__ void wave_argmax(float& v, int& i) {
#pragma unroll
  for (int off = 32; off > 0; off >>= 1) {
    float ov = __shfl_down(v, off);
    int   oi = __shfl_down(i, off);
    if (better(ov, oi, v, i)) { v = ov; i = oi; }
  }
}

// merge this lane's sorted-desc 8-list with partner lane's (xor off); both keep top-8
__device__ __forceinline__ void xor_merge8(float* m, int* mi, int off) {
  float lb[8]; int ib8[8];
#pragma unroll
  for (int k = 0; k < 8; k++) { lb[k] = __shfl_xor(m[k], off); ib8[k] = __shfl_xor(mi[k], off); }
  float x[8]; int xi[8];
#pragma unroll
  for (int k = 0; k < 8; k++) {   // top half of merged 16 (bitonic)
    const bool ta = better(m[k], mi[k], lb[7 - k], ib8[7 - k]);
    x[k]  = ta ? m[k]  : lb[7 - k];
    xi[k] = ta ? mi[k] : ib8[7 - k];
  }
  // bitonic clean desc: strides 4,2,1
  cswap(x[0], xi[0], x[4], xi[4]); cswap(x[1], xi[1], x[5], xi[5]);
  cswap(x[2], xi[2], x[6], xi[6]); cswap(x[3], xi[3], x[7], xi[7]);
  cswap(x[0], xi[0], x[2], xi[2]); cswap(x[1], xi[1], x[3], xi[3]);
  cswap(x[4], xi[4], x[6], xi[6]); cswap(x[5], xi[5], x[7], xi[7]);
  cswap(x[0], xi[0], x[1], xi[1]); cswap(x[2], xi[2], x[3], xi[3]);
  cswap(x[4], xi[4], x[5], xi[5]); cswap(x[6], xi[6], x[7], xi[7]);
#pragma unroll
  for (int k = 0; k < 8; k++) { m[k] = x[k]; mi[k] = xi[k]; }
}

// ---------------- K1: blocks 0..63 = S-chain + R (longest pole, dispatched first);
//                     blocks 64..575 = (batch, slice) selection; first 256 also do a P2 quarter ----------------
__global__ __launch_bounds__(256) void k_scan(
    const float* __restrict__ cpc, const float* __restrict__ times,
    const float* __restrict__ lookup,
    const float* __restrict__ proj, const float* __restrict__ Amat,
    const float* __restrict__ Bmat, const float* __restrict__ Cmat,
    const float* __restrict__ Dmat,
    float* __restrict__ P2, float* __restrict__ R,
    float* __restrict__ pmax, float* __restrict__ psum,
    float* __restrict__ pcv, int* __restrict__ pci,
    int* __restrict__ pshift) {
  const int t = threadIdx.x;
  const int bid = blockIdx.x;

  // chain-path LDS (sred8 is reused by the slice path's P2 reduction)
  __shared__ __align__(16) float sjall[SD * 8];   // 4 KB, [i][j] layout for float4 broadcast
  __shared__ __align__(16) float sred8[8 * SD];   // 4 KB, K-octant partials (float4-writes)
  __shared__ float sb[2][SD];
  // slice-path LDS (small)
  __shared__ float wred[4];
  __shared__ int   wredi[4];
  __shared__ int   sRow;
  __shared__ float wlv[32];
  __shared__ int   wli[32];
  __shared__ float sSmax;

  if (bid < CPD) {
    // ----- S-chain: s_j = proj_c @ B @ A^j, then R[j,c,:] = s_j @ C -----
    // float4-widened GEMVs (r7 proven lever).
    const int c = bid;
    const int dg = t & 31;   // d-group: columns 4*dg .. 4*dg+3
    const int h  = t >> 5;   // K-octant

    // --- B-pass: s0[d] = sum_k p[k] * B[k][d], K split 8 ways ---
    {
      const float4* B4 = (const float4*)Bmat + dg;                     // + k*32 per row
      const float4* P4 = (const float4*)(proj + (size_t)c * WSZ + h * 64);
      float4 a0 = {0.f, 0.f, 0.f, 0.f}, a1 = a0, a2 = a0, a3 = a0;
#pragma unroll 4
      for (int kb = 0; kb < 64; kb += 4) {
        const float4 pv = P4[kb >> 2];
        const float4 q0 = B4[(size_t)(h * 64 + kb + 0) * 32];
        const float4 q1 = B4[(size_t)(h * 64 + kb + 1) * 32];
        const float4 q2 = B4[(size_t)(h * 64 + kb + 2) * 32];
        const float4 q3 = B4[(size_t)(h * 64 + kb + 3) * 32];
        a0.x = fmaf(pv.x, q0.x, a0.x); a0.y = fmaf(pv.x, q0.y, a0.y);
        a0.z = fmaf(pv.x, q0.z, a0.z); a0.w = fmaf(pv.x, q0.w, a0.w);
        a1.x = fmaf(pv.y, q1.x, a1.x); a1.y = fmaf(pv.y, q1.y, a1.y);
        a1.z = fmaf(pv.y, q1.z, a1.z); a1.w = fmaf(pv.y, q1.w, a1.w);
        a2.x = fmaf(pv.z, q2.x, a2.x); a2.y = fmaf(pv.z, q2.y, a2.y);
        a2.z = fmaf(pv.z, q2.z, a2.z); a2.w = fmaf(pv.z, q2.w, a2.w);
        a3.x = fmaf(pv.w, q3.x, a3.x); a3.y = fmaf(pv.w, q3.y, a3.y);
        a3.z = fmaf(pv.w, q3.z, a3.z); a3.w = fmaf(pv.w, q3.w, a3.w);
      }
      float4 s4;
      s4.x = (a0.x + a1.x) + (a2.x + a3.x);
      s4.y = (a0.y + a1.y) + (a2.y + a3.y);
      s4.z = (a0.z + a1.z) + (a2.z + a3.z);
      s4.w = (a0.w + a1.w) + (a2.w + a3.w);
      ((float4*)sred8)[h * 32 + dg] = s4;
    }
    __syncthreads();
    if (t < SD) {
      sb[0][t] = ((sred8[t] + sred8[SD + t]) + (sred8[2 * SD + t] + sred8[3 * SD + t]))
               + ((sred8[4 * SD + t] + sred8[5 * SD + t]) + (sred8[6 * SD + t] + sred8[7 * SD + t]));
    }
    __syncthreads();

    // --- j-loop: s' = s @ A, 16 float4 A-loads/thread/step (one latency batch) ---
    int cur = 0;
    const float4* A4 = (const float4*)Amat + dg;                       // + i*32 per row
    for (int j = 0; j < TPROP; j++) {
      if (t < SD) sjall[t * 8 + j] = sb[cur][t];
      float4 av = {0.f, 0.f, 0.f, 0.f}, bv = av;
      const float* sh = sb[cur] + h * 16;
#pragma unroll
      for (int i = 0; i < 16; i += 2) {
        const float s0v = sh[i], s1v = sh[i + 1];
        const float4 q0 = A4[(size_t)(h * 16 + i) * 32];
        const float4 q1 = A4[(size_t)(h * 16 + i + 1) * 32];
        av.x = fmaf(s0v, q0.x, av.x); av.y = fmaf(s0v, q0.y, av.y);
        av.z = fmaf(s0v, q0.z, av.z); av.w = fmaf(s0v, q0.w, av.w);
        bv.x = fmaf(s1v, q1.x, bv.x); bv.y = fmaf(s1v, q1.y, bv.y);
        bv.z = fmaf(s1v, q1.z, bv.z); bv.w = fmaf(s1v, q1.w, bv.w);
      }
      float4 s4;
      s4.x = av.x + bv.x; s4.y = av.y + bv.y; s4.z = av.z + bv.z; s4.w = av.w + bv.w;
      ((float4*)sred8)[h * 32 + dg] = s4;
      __syncthreads();
      if (t < SD) {
        sb[cur ^ 1][t] = ((sred8[t] + sred8[SD + t]) + (sred8[2 * SD + t] + sred8[3 * SD + t]))
                       + ((sred8[4 * SD + t] + sred8[5 * SD + t]) + (sred8[6 * SD + t] + sred8[7 * SD + t]));
      }
      __syncthreads();
      cur ^= 1;
    }

    // --- R pass: R[j,c,w] = sum_i s_j[i] * C[i][w]; thread = (w-group, j-half).
    //     unroll 16 (r9): 16 C-loads in flight -> 8 serial latency batches (was 32).
    //     Per-accumulator fma chains keep i-order -> bit-identical results. ---
    {
      const int wg = t & 127;            // w-group: columns 4*wg .. 4*wg+3
      const int jh = (t >> 7) * 4;       // j base: 0 or 4
      float4 r4[4];
#pragma unroll
      for (int k = 0; k < 4; k++) r4[k] = make_float4(0.f, 0.f, 0.f, 0.f);
      const float4* C4 = (const float4*)Cmat + wg;                     // + i*128 per row
#pragma unroll 16
      for (int i = 0; i < SD; i++) {
        const float4 cv = C4[(size_t)i * 128];
        const float4 sj = *(const float4*)(sjall + i * 8 + jh);
        r4[0].x = fmaf(sj.x, cv.x, r4[0].x); r4[0].y = fmaf(sj.x, cv.y, r4[0].y);
        r4[0].z = fmaf(sj.x, cv.z, r4[0].z); r4[0].w = fmaf(sj.x, cv.w, r4[0].w);
        r4[1].x = fmaf(sj.y, cv.x, r4[1].x); r4[1].y = fmaf(sj.y, cv.y, r4[1].y);
        r4[1].z = fmaf(sj.y, cv.z, r4[1].z); r4[1].w = fmaf(sj.y, cv.w, r4[1].w);
        r4[2].x = fmaf(sj.z, cv.x, r4[2].x); r4[2].y = fmaf(sj.z, cv.y, r4[2].y);
        r4[2].z = fmaf(sj.z, cv.z, r4[2].z); r4[2].w = fmaf(sj.z, cv.w, r4[2].w);
        r4[3].x = fmaf(sj.w, cv.x, r4[3].x); r4[3].y = fmaf(sj.w, cv.y, r4[3].y);
        r4[3].z = fmaf(sj.w, cv.z, r4[3].z); r4[3].w = fmaf(sj.w, cv.w, r4[3].w);
      }
#pragma unroll
      for (int jj = 0; jj < 4; jj++)
        *(float4*)(R + ((size_t)((jh + jj) * CPD + c)) * WSZ + wg * 4) = r4[jj];
    }
    return;
  }

  const int sbid = bid - CPD;
  const int b = sbid >> 3, s = sbid & 7;
  const int lane = t & 63, wv = t >> 6;

  // --- cpc argmax (redundant across the 8 slice blocks; 2 KB, cheap) ---
  {
    float v0 = cpc[b * NCP + t];
    float v1 = cpc[b * NCP + t + 256];
    float bv = v0; int bi = t;
    if (better(v1, t + 256, bv, bi)) { bv = v1; bi = t + 256; }
    wave_argmax(bv, bi);
    if (lane == 0) { wred[wv] = bv; wredi[wv] = bi; }
    __syncthreads();
    if (t == 0) {
      float fv = wred[0]; int fi = wredi[0];
#pragma unroll
      for (int q = 1; q < 4; q++)
        if (better(wred[q], wredi[q], fv, fi)) { fv = wred[q]; fi = wredi[q]; }
      sRow = fi;
    }
    __syncthreads();
  }
  const float* row = lookup + (size_t)sRow * (CPD * NF);
  const float4* row4 = (const float4*)(row + s * SLICE_ELEMS);

  // --- load 8 elements (2 independent float4) ---
  const float4 va = row4[t];
  const float4 vb = row4[t + 256];
  const int gbase = s * SLICE_ELEMS;
  float ev[8] = {va.x, va.y, va.z, va.w, vb.x, vb.y, vb.z, vb.w};
  int   ei[8] = {gbase + t * 4,        gbase + t * 4 + 1,
                 gbase + t * 4 + 2,    gbase + t * 4 + 3,
                 gbase + 1024 + t * 4, gbase + 1024 + t * 4 + 1,
                 gbase + 1024 + t * 4 + 2, gbase + 1024 + t * 4 + 3};

  // --- per-thread sort desc (static bubble network, registers) ---
  float m[8]; int mi[8];
#pragma unroll
  for (int k = 0; k < 8; k++) { m[k] = ev[k]; mi[k] = ei[k]; }
#pragma unroll
  for (int i = 0; i < 7; i++)
#pragma unroll
    for (int j = 0; j < 7 - i; j++) cswap(m[j], mi[j], m[j + 1], mi[j + 1]);

  // --- wave-level merge: 6 shuffle rounds, no barriers, no LDS ---
  xor_merge8(m, mi, 1);  xor_merge8(m, mi, 2);  xor_merge8(m, mi, 4);
  xor_merge8(m, mi, 8);  xor_merge8(m, mi, 16); xor_merge8(m, mi, 32);

  if (lane < 8) { wlv[wv * 8 + lane] = m[lane]; wli[wv * 8 + lane] = mi[lane]; }
  __syncthreads();

  // --- wave 0: bitonic sort-32 of the 4 wave lists via shuffles ---
  if (wv == 0) {
    float v = (lane < 32) ? wlv[lane] : -3.4e38f;
    int   i = (lane < 32) ? wli[lane] : 0x7fffffff;
#pragma unroll
    for (int k = 2; k <= 32; k <<= 1) {
#pragma unroll
      for (int j = k >> 1; j > 0; j >>= 1) {
        const float pv = __shfl_xor(v, j);
        const int   pi = __shfl_xor(i, j);
        const bool keepBetter = (((lane & k) == 0) == ((lane & j) == 0));
        if (keepBetter == better(pv, pi, v, i)) { v = pv; i = pi; }
      }
    }
    if (lane == 0) sSmax = v;
    if (lane < 8) { pcv[b * 64 + s * 8 + lane] = v; pci[b * 64 + s * 8 + lane] = i; }
  }
  __syncthreads();
  const float smax = sSmax;

  // --- partial exp-sum (8 independent exps per thread) ---
  float se = 0.f;
#pragma unroll
  for (int k = 0; k < 8; k++) se += __expf(ev[k] - smax);
#pragma unroll
  for (int off = 32; off > 0; off >>= 1) se += __shfl_down(se, off);
  if (lane == 0) wred[wv] = se;
  __syncthreads();
  if (t == 0) {
    pmax[b * 8 + s] = smax;
    psum[b * 8 + s] = (wred[0] + wred[1]) + (wred[2] + wred[3]);
  }
  __syncthreads();  // protect wred against reuse below

  // --- dirac shift (slice 0 only): argmax over times[b,0,:256] ---
  if (s == 0) {
    float tv = times[b * NF + t]; int ti = t;
    wave_argmax(tv, ti);
    if (lane == 0) { wred[wv] = tv; wredi[wv] = ti; }
    __syncthreads();
    if (t == 0) {
      float fv = wred[0]; int fi = wredi[0];
#pragma unroll
      for (int q = 1; q < 4; q++)
        if (better(wred[q], wredi[q], fv, fi)) { fv = wred[q]; fi = wredi[q]; }
      pshift[b] = fi * (NSAMP / NF);
    }
  }

  // --- P2 quarter-row (first 256 slice blocks): P2[c2, q*128 : +128] = proj[c2,:] @ D[:, cols]
  //     float4-widened (r7/r8 lever): 64 float4 D-loads/thread vs 256 scalar; 8-way K-split
  //     reduced through sred8 (reused from the chain path's LDS). ---
  if (sbid < 256) {
    const int c2 = sbid >> 2, q = sbid & 3;
    const int cg = t & 31;   // col-group within the 128-col quarter: cols 4*cg .. 4*cg+3
    const int uh = t >> 5;   // K-octant: rows uh*64 .. uh*64+63
    const float4* D4 = (const float4*)Dmat + q * 32 + cg;              // + u*128 per row
    const float4* P4 = (const float4*)(proj + (size_t)c2 * WSZ + uh * 64);
    float4 a0 = {0.f, 0.f, 0.f, 0.f}, a1 = a0, a2 = a0, a3 = a0;
#pragma unroll 4
    for (int ub = 0; ub < 64; ub += 4) {
      const float4 pv = P4[ub >> 2];
      const float4 q0 = D4[(size_t)(uh * 64 + ub + 0) * 128];
      const float4 q1 = D4[(size_t)(uh * 64 + ub + 1) * 128];
      const float4 q2 = D4[(size_t)(uh * 64 + ub + 2) * 128];
      const float4 q3 = D4[(size_t)(uh * 64 + ub + 3) * 128];
      a0.x = fmaf(pv.x, q0.x, a0.x); a0.y = fmaf(pv.x, q0.y, a0.y);
      a0.z = fmaf(pv.x, q0.z, a0.z); a0.w = fmaf(pv.x, q0.w, a0.w);
      a1.x = fmaf(pv.y, q1.x, a1.x); a1.y = fmaf(pv.y, q1.y, a1.y);
      a1.z = fmaf(pv.y, q1.z, a1.z); a1.w = fmaf(pv.y, q1.w, a1.w);
      a2.x = fmaf(pv.z, q2.x, a2.x); a2.y = fmaf(pv.z, q2.y, a2.y);
      a2.z = fmaf(pv.z, q2.z, a2.z); a2.w = fmaf(pv.z, q2.w, a2.w);
      a3.x = fmaf(pv.w, q3.x, a3.x); a3.y = fmaf(pv.w, q3.y, a3.y);
      a3.z = fmaf(pv.w, q3.z, a3.z); a3.w = fmaf(pv.w, q3.w, a3.w);
    }
    float4 s4;
    s4.x = (a0.x + a1.x) + (a2.x + a3.x);
    s4.y = (a0.y + a1.y) + (a2.y + a3.y);
    s4.z = (a0.z + a1.z) + (a2.z + a3.z);
    s4.w = (a0.w + a1.w) + (a2.w + a3.w);
    ((float4*)sred8)[uh * 32 + cg] = s4;
    __syncthreads();
    if (t < 128) {
      const float r = ((sred8[t] + sred8[128 + t]) + (sred8[256 + t] + sred8[384 + t]))
                    + ((sred8[512 + t] + sred8[640 + t]) + (sred8[768 + t] + sred8[896 + t]));
      P2[(size_t)c2 * WSZ + q * 128 + t] = r;
    }
  }
}

// ---------------- K2: per-block redundant top-8 combine (1 wave, deterministic) + output assembly ----------------
// 2048 blocks: 32 per batch, each covering 2048 samples (two float4 per thread)
__global__ __launch_bounds__(256) void k_out(
    const float* __restrict__ pmax, const float* __restrict__ psum,
    const float* __restrict__ pcv, const int* __restrict__ pci,
    const int* __restrict__ pshift,
    const float* __restrict__ P2, const float* __restrict__ R,
    float* __restrict__ out) {
  const int b = blockIdx.x >> 5;        // 32 blocks per batch
  const int chunk = blockIdx.x & 31;
  const int t = threadIdx.x;
  __shared__ float lv[8];
  __shared__ int   lc[8];
  __shared__ int   lf[8];

  const int shift = pshift[b];          // issue early: latency hides under the combine

  // Early exit: out[n] = samples[n-shift], zero for n < shift. If this block's whole
  // 2048-sample range is below shift (avg ~half of all blocks for random times),
  // skip the ~600cy combine + gathers entirely. shift is block-uniform -> safe return.
  if (chunk * 2048 + 2047 < shift) {
    const float4 z = make_float4(0.f, 0.f, 0.f, 0.f);
    float* ob = out + (size_t)b * NSAMP + chunk * 2048;
    *(float4*)(ob + t * 4) = z;
    *(float4*)(ob + 1024 + t * 4) = z;
    return;
  }

  if (t < 64) {
    // merge 8 slice top-8 lists for batch b (identical in every block of this batch)
    const int sl = t >> 3;
    float M = pmax[b * 8 + sl];
#pragma unroll
    for (int off = 1; off < 64; off <<= 1) M = fmaxf(M, __shfl_xor(M, off));
    float ps = ((t & 7) == 0) ? psum[b * 8 + sl] * __expf(pmax[b * 8 + sl] - M) : 0.f;
#pragma unroll
    for (int off = 1; off < 64; off <<= 1) ps += __shfl_xor(ps, off);
    float cvv = pcv[b * 64 + t]; int cii = pci[b * 64 + t];
    for (int p = 0; p < 8; p++) {
      float v = cvv; int i = cii;
#pragma unroll
      for (int off = 1; off < 64; off <<= 1) {
        float ov = __shfl_xor(v, off); int oi = __shfl_xor(i, off);
        if (better(ov, oi, v, i)) { v = ov; i = oi; }
      }
      if (t == 0) {
        lv[p] = __expf(v - M) / ps;
        lc[p] = i / NF;
        lf[p] = i % NF;
      }
      if (cii == i) cvv = -3.4e38f;
    }
  }
  __syncthreads();

#pragma unroll 2
  for (int half = 0; half < 2; half++) {
    const int n = chunk * 2048 + half * 1024 + t * 4;  // 4 samples per thread per half
    const int m = n - shift;              // shift is a multiple of 256 -> all 4 samples share frames
    float o[4] = {0.f, 0.f, 0.f, 0.f};
    if (m >= 0) {
      const int f1 = m >> 8;
      const int w1 = m & 255;
      float a[4] = {0.f, 0.f, 0.f, 0.f};
      float g[4] = {0.f, 0.f, 0.f, 0.f};
      const bool hasf2 = (f1 > 0);
#pragma unroll
      for (int k = 0; k < 8; k++) {
        const float v = lv[k];
        const int c = lc[k];
        const int d1 = f1 - lf[k];
        if (d1 >= 0 && d1 < TPROP) {
          const float4 q = *(const float4*)(R + ((size_t)(d1 * CPD + c)) * WSZ + w1);
          a[0] += v * q.x; a[1] += v * q.y; a[2] += v * q.z; a[3] += v * q.w;
        }
        if (d1 == 0) {
          const float4 q = *(const float4*)(P2 + (size_t)c * WSZ + w1);
          a[0] += v * q.x; a[1] += v * q.y; a[2] += v * q.z; a[3] += v * q.w;
        }
        if (hasf2) {
          const int d2 = d1 - 1;
          if (d2 >= 0 && d2 < TPROP) {
            const float4 q = *(const float4*)(R + ((size_t)(d2 * CPD + c)) * WSZ + w1 + 256);
            g[0] += v * q.x; g[1] += v * q.y; g[2] += v * q.z; g[3] += v * q.w;
          }
          if (d2 == 0) {
            const float4 q = *(const float4*)(P2 + (size_t)c * WSZ + w1 + 256);
            g[0] += v * q.x; g[1] += v * q.y; g[2] += v * q.z; g[3] += v * q.w;
          }
        }
      }
      const float k2pi = 6.283185307179586f / (float)WSZ;
#pragma unroll
      for (int i = 0; i < 4; i++) {
        const float cs = __cosf(k2pi * (float)(w1 + i));
        const float wa = 0.5f * (1.f - cs);
        const float wb = 0.5f * (1.f + cs);
        o[i] = wa * a[i] + wb * g[i];
      }
    }
    float4 ov = make_float4(o[0], o[1], o[2], o[3]);
    *(float4*)(out + (size_t)b * NSAMP + n) = ov;
  }
}

extern "C" void kernel_launch(void* const* d_in, const int* in_sizes, int n_in,
                              void* d_out, int out_size, void* d_ws, size_t ws_size,
                              hipStream_t stream) {
  const float* cpc    = (const float*)d_in[0];
  const float* times  = (const float*)d_in[1];
  const float* lookup = (const float*)d_in[2];
  const float* proj   = (const float*)d_in[3];
  const float* Amat   = (const float*)d_in[4];
  const float* Bmat   = (const float*)d_in[5];
  const float* Cmat   = (const float*)d_in[6];
  const float* Dmat   = (const float*)d_in[7];
  float* out = (float*)d_out;

  // ws floats: [1536 reserved] pshift[64] P2[32768] R[262144] [S region unused]
  //            pmax[512] psum[512] pcv[4096] pci[4096]
  float* w      = (float*)d_ws;
  int*   pshift = (int*)(w + 1536);
  float* P2     = w + 1600;
  float* R      = P2 + CPD * WSZ;
  float* S_unused = R + (size_t)TPROP * CPD * WSZ;
  float* pmax   = S_unused + (size_t)TPROP * CPD * SD;
  float* psum   = pmax + NBATCH * NSLICE;
  float* pcv    = psum + NBATCH * NSLICE;
  int*   pci    = (int*)(pcv + NBATCH * NSLICE * 8);

  hipLaunchKernelGGL(k_scan, dim3(CPD + NBATCH * NSLICE), dim3(256), 0, stream,
                     cpc, times, lookup, proj, Amat, Bmat, Cmat, Dmat,
                     P2, R, pmax, psum, pcv, pci, pshift);
  hipLaunchKernelGGL(k_out, dim3(NBATCH * 32), dim3(256), 0, stream,
                     pmax, psum, pcv, pci, pshift, P2, R, out);
}